// Round 1
// baseline (51438.837 us; speedup 1.0000x reference)
//
#include <hip/hip_runtime.h>

// ---------------------------------------------------------------------------
// VGG_DC: 7x fp32 conv3x3(pad=2,+align-6 width)+ReLU with maxpools, int cast,
// 6x int DC conv3x3(valid, A&31, 5-bit W), maxpools, mean-pool + FC(512->1000).
// Correctness-first round: direct conv, fp32 float path (int-flip safety),
// exact int32 DC path. Ping-pong workspace, batch-chunked to fit ws_size.
// ---------------------------------------------------------------------------

#define CONV_TW 4   // outputs along W per thread
#define CONV_TCO 4  // output channels per thread

// ---------------- float conv 3x3, pad=2 (with align-6 zero extension) -------
// Wout = align6(Win)+2, Hout = Hin+2. Reads beyond Win/Hin are zero.
__global__ __launch_bounds__(256) void conv3x3_relu_k(
    const float* __restrict__ in, const float* __restrict__ wgt,
    const float* __restrict__ bias, float* __restrict__ out,
    int Cin, int Hin, int Win, int Cout, int Hout, int Wout, int WoutB)
{
    const int s = blockIdx.x * 256 + threadIdx.x;
    if (s >= Hout * WoutB) return;
    const int w0 = (s % WoutB) * CONV_TW;
    const int h  = s / WoutB;
    const int CoutB = Cout / CONV_TCO;
    const int n   = blockIdx.z / CoutB;
    const int co0 = (blockIdx.z % CoutB) * CONV_TCO;   // uniform per block -> scalar weight loads

    const float* inN = in + (size_t)n * Cin * Hin * Win;
    float acc[CONV_TCO][CONV_TW];
#pragma unroll
    for (int c = 0; c < CONV_TCO; ++c)
#pragma unroll
        for (int t = 0; t < CONV_TW; ++t) acc[c][t] = 0.f;

    for (int ci = 0; ci < Cin; ++ci) {
        const float* ip = inN + (size_t)ci * Hin * Win;
        const float* wp = wgt + ((size_t)co0 * Cin + ci) * 9;
#pragma unroll
        for (int kh = 0; kh < 3; ++kh) {
            const int y = h - 2 + kh;
            const bool yok = (unsigned)y < (unsigned)Hin;
            const int yc = y < 0 ? 0 : (y >= Hin ? Hin - 1 : y);
            const float* row = ip + (size_t)yc * Win;
            float v[CONV_TW + 2];
#pragma unroll
            for (int j = 0; j < CONV_TW + 2; ++j) {
                const int xx = w0 - 2 + j;
                const int xc = xx < 0 ? 0 : (xx >= Win ? Win - 1 : xx);
                const float tv = row[xc];                   // clamped: always in-bounds
                v[j] = (yok && (unsigned)xx < (unsigned)Win) ? tv : 0.f;
            }
#pragma unroll
            for (int c = 0; c < CONV_TCO; ++c) {
                const float* wr = wp + (size_t)c * (size_t)Cin * 9 + kh * 3;
                const float k0 = wr[0], k1 = wr[1], k2 = wr[2];
#pragma unroll
                for (int t = 0; t < CONV_TW; ++t)
                    acc[c][t] = fmaf(v[t], k0, fmaf(v[t + 1], k1, fmaf(v[t + 2], k2, acc[c][t])));
            }
        }
    }

    const size_t plane = (size_t)Hout * Wout;
    const size_t ob = ((size_t)n * Cout + co0) * plane + (size_t)h * Wout + w0;
#pragma unroll
    for (int c = 0; c < CONV_TCO; ++c) {
        const float b = bias[co0 + c];
#pragma unroll
        for (int t = 0; t < CONV_TW; ++t) {
            if (w0 + t < Wout) {
                const float r = acc[c][t] + b;
                out[ob + (size_t)c * plane + t] = r > 0.f ? r : 0.f;
            }
        }
    }
}

// ---------------- int DC conv 3x3, valid (with align-6 zero extension) ------
// Wout = align6(Win)-2, Hout = Hin-2. a&31; weights 0..30 (&255 for u24 proof).
__global__ __launch_bounds__(256) void dcconv3x3_k(
    const int* __restrict__ in, const int* __restrict__ wgt, int* __restrict__ out,
    int Cin, int Hin, int Win, int Cout, int Hout, int Wout, int WoutB)
{
    const int s = blockIdx.x * 256 + threadIdx.x;
    if (s >= Hout * WoutB) return;
    const int w0 = (s % WoutB) * CONV_TW;
    const int h  = s / WoutB;
    const int CoutB = Cout / CONV_TCO;
    const int n   = blockIdx.z / CoutB;
    const int co0 = (blockIdx.z % CoutB) * CONV_TCO;

    const int* inN = in + (size_t)n * Cin * Hin * Win;
    int acc[CONV_TCO][CONV_TW];
#pragma unroll
    for (int c = 0; c < CONV_TCO; ++c)
#pragma unroll
        for (int t = 0; t < CONV_TW; ++t) acc[c][t] = 0;

    for (int ci = 0; ci < Cin; ++ci) {
        const int* ip = inN + (size_t)ci * Hin * Win;
        const int* wp = wgt + ((size_t)co0 * Cin + ci) * 9;
#pragma unroll
        for (int kh = 0; kh < 3; ++kh) {
            const int* row = ip + (size_t)(h + kh) * Win;   // y always in range (valid conv)
            int v[CONV_TW + 2];
#pragma unroll
            for (int j = 0; j < CONV_TW + 2; ++j) {
                const int xx = w0 + j;
                const int xc = xx < Win ? xx : Win - 1;
                const int tv = row[xc] & 31;                // A_MASK
                v[j] = (xx < Win) ? tv : 0;                 // align-6 zero pad
            }
#pragma unroll
            for (int c = 0; c < CONV_TCO; ++c) {
                const int* wr = wp + (size_t)c * (size_t)Cin * 9 + kh * 3;
                const int k0 = wr[0] & 255, k1 = wr[1] & 255, k2 = wr[2] & 255;
#pragma unroll
                for (int t = 0; t < CONV_TW; ++t)
                    acc[c][t] += v[t] * k0 + v[t + 1] * k1 + v[t + 2] * k2;
            }
        }
    }

    const size_t plane = (size_t)Hout * Wout;
    const size_t ob = ((size_t)n * Cout + co0) * plane + (size_t)h * Wout + w0;
#pragma unroll
    for (int c = 0; c < CONV_TCO; ++c)
#pragma unroll
        for (int t = 0; t < CONV_TW; ++t)
            if (w0 + t < Wout) out[ob + (size_t)c * plane + t] = acc[c][t];
}

// ---------------- maxpool 2x2 stride 2 (VALID) ------------------------------
__global__ void maxpool2_f32_k(const float* __restrict__ in, float* __restrict__ out,
                               int C, int Hin, int Win, int Hout, int Wout, int total)
{
    const int i = blockIdx.x * 256 + threadIdx.x;
    if (i >= total) return;
    int t = i;
    const int w = t % Wout; t /= Wout;
    const int h = t % Hout; t /= Hout;
    const int c = t % C;    const int n = t / C;
    const float* p = in + (((size_t)n * C + c) * Hin + 2 * h) * Win + 2 * w;
    out[i] = fmaxf(fmaxf(p[0], p[1]), fmaxf(p[Win], p[Win + 1]));
}

__global__ void maxpool2_f32_to_i32_k(const float* __restrict__ in, int* __restrict__ out,
                                      int C, int Hin, int Win, int Hout, int Wout, int total)
{
    const int i = blockIdx.x * 256 + threadIdx.x;
    if (i >= total) return;
    int t = i;
    const int w = t % Wout; t /= Wout;
    const int h = t % Hout; t /= Hout;
    const int c = t % C;    const int n = t / C;
    const float* p = in + (((size_t)n * C + c) * Hin + 2 * h) * Win + 2 * w;
    const float m = fmaxf(fmaxf(p[0], p[1]), fmaxf(p[Win], p[Win + 1]));
    out[i] = (int)m;   // truncation toward zero; m >= 0 after ReLU
}

__global__ void maxpool2_i32_k(const int* __restrict__ in, int* __restrict__ out,
                               int C, int Hin, int Win, int Hout, int Wout, int total)
{
    const int i = blockIdx.x * 256 + threadIdx.x;
    if (i >= total) return;
    int t = i;
    const int w = t % Wout; t /= Wout;
    const int h = t % Hout; t /= Hout;
    const int c = t % C;    const int n = t / C;
    const int* p = in + (((size_t)n * C + c) * Hin + 2 * h) * Win + 2 * w;
    int m = p[0];
    m = max(m, p[1]); m = max(m, p[Win]); m = max(m, p[Win + 1]);
    out[i] = m;
}

// ---------------- head: mean over 3x11 spatial, then FC ---------------------
__global__ void pool_mean_k(const int* __restrict__ in, float* __restrict__ out, int total)
{
    const int i = blockIdx.x * 256 + threadIdx.x;   // total = nb*512
    if (i >= total) return;
    const int* p = in + (size_t)i * 33;
    int s = 0;
#pragma unroll
    for (int j = 0; j < 33; ++j) s += p[j];
    out[i] = (float)s / 33.0f;
}

__global__ void fc_k(const float* __restrict__ pooled, const float* __restrict__ w,
                     const float* __restrict__ b, float* __restrict__ out, int nb, int n0)
{
    const int i = blockIdx.x * 256 + threadIdx.x;   // nb*1000
    if (i >= nb * 1000) return;
    const int co = i % 1000;
    const int n  = i / 1000;
    const float* pv = pooled + (size_t)n * 512;
    const float* wr = w + (size_t)co * 512;
    float s = b[co];
    for (int c = 0; c < 512; ++c) s = fmaf(pv[c], wr[c], s);
    out[(size_t)(n0 + n) * 1000 + co] = s;
}

// ---------------------------------------------------------------------------
struct ConvDim { int Cin, Hin, Win, Cout, Hout, Wout; };
static const ConvDim FL[7] = {
    {  3, 224, 224,  64, 226, 230},
    { 64, 226, 230,  64, 228, 236},
    { 64, 114, 118, 128, 116, 122},
    {128, 116, 122, 128, 118, 128},
    {128,  59,  64, 256,  61,  68},
    {256,  61,  68, 256,  63,  74},
    {256,  63,  74, 256,  65,  80},
};
static const ConvDim DC[6] = {
    {256, 32, 40, 512, 30, 40},
    {512, 30, 40, 512, 28, 40},
    {512, 28, 40, 512, 26, 40},
    {512, 13, 20, 512, 11, 22},
    {512, 11, 22, 512,  9, 22},
    {512,  9, 22, 512,  7, 22},
};

extern "C" void kernel_launch(void* const* d_in, const int* in_sizes, int n_in,
                              void* d_out, int out_size, void* d_ws, size_t ws_size,
                              hipStream_t stream)
{
    (void)n_in; (void)out_size;
    const float* x = (const float*)d_in[0];
    const float* W[7]; const float* Bv[7]; const int* Q[6];
    const bool inter = (in_sizes[2] == 64);   // dict order: x,w1,b1,w2,b2,... ; else grouped
    for (int i = 0; i < 7; ++i) {
        if (inter) { W[i] = (const float*)d_in[1 + 2 * i]; Bv[i] = (const float*)d_in[2 + 2 * i]; }
        else       { W[i] = (const float*)d_in[1 + i];     Bv[i] = (const float*)d_in[8 + i];     }
    }
    for (int i = 0; i < 6; ++i) Q[i] = (const int*)d_in[15 + i];
    const float* fcw = (const float*)d_in[21];
    const float* fcb = (const float*)d_in[22];
    float* outp = (float*)d_out;

    // per-image ping-pong regions (max intermediate = 13.78 MB)
    const size_t SA = 14ull << 20;
    int chunk = 16;
    while (chunk > 1 && (2ull * (size_t)chunk * SA + 65536) > ws_size) chunk >>= 1;

    char* wsb = (char*)d_ws;

    auto conv = [&](const float* src, const ConvDim& d, int li, float* dst, int nb) {
        const int WoutB = (d.Wout + CONV_TW - 1) / CONV_TW;
        const int gx = (d.Hout * WoutB + 255) / 256;
        dim3 grid(gx, 1, nb * (d.Cout / CONV_TCO));
        conv3x3_relu_k<<<grid, 256, 0, stream>>>(src, W[li], Bv[li], dst,
            d.Cin, d.Hin, d.Win, d.Cout, d.Hout, d.Wout, WoutB);
    };
    auto dcconv = [&](const int* src, const ConvDim& d, int li, int* dst, int nb) {
        const int WoutB = (d.Wout + CONV_TW - 1) / CONV_TW;
        const int gx = (d.Hout * WoutB + 255) / 256;
        dim3 grid(gx, 1, nb * (d.Cout / CONV_TCO));
        dcconv3x3_k<<<grid, 256, 0, stream>>>(src, Q[li], dst,
            d.Cin, d.Hin, d.Win, d.Cout, d.Hout, d.Wout, WoutB);
    };

    for (int n0 = 0; n0 < 16; n0 += chunk) {
        const int nb = chunk;
        float* A  = (float*)wsb;
        float* Bb = (float*)(wsb + (size_t)chunk * SA);
        float* P  = (float*)(wsb + 2ull * (size_t)chunk * SA);

        const float* cur = x + (size_t)n0 * 3 * 224 * 224;

        conv(cur, FL[0], 0, A, nb);               // L1: x -> A (64,226,230)
        conv(A,   FL[1], 1, Bb, nb);              // L2: A -> B (64,228,236)
        {   // P1: B -> A (64,114,118)
            const int total = nb * 64 * 114 * 118;
            maxpool2_f32_k<<<(total + 255) / 256, 256, 0, stream>>>(Bb, A, 64, 228, 236, 114, 118, total);
        }
        conv(A,  FL[2], 2, Bb, nb);               // L3: A -> B (128,116,122)
        conv(Bb, FL[3], 3, A,  nb);               // L4: B -> A (128,118,128)
        {   // P2: A -> B (128,59,64)
            const int total = nb * 128 * 59 * 64;
            maxpool2_f32_k<<<(total + 255) / 256, 256, 0, stream>>>(A, Bb, 128, 118, 128, 59, 64, total);
        }
        conv(Bb, FL[4], 4, A,  nb);               // L5: B -> A (256,61,68)
        conv(A,  FL[5], 5, Bb, nb);               // L6: A -> B (256,63,74)
        conv(Bb, FL[6], 6, A,  nb);               // L7: B -> A (256,65,80)
        {   // P3 + int cast: A -> B (256,32,40) int32
            const int total = nb * 256 * 32 * 40;
            maxpool2_f32_to_i32_k<<<(total + 255) / 256, 256, 0, stream>>>(A, (int*)Bb, 256, 65, 80, 32, 40, total);
        }
        dcconv((const int*)Bb, DC[0], 0, (int*)A,  nb);   // D1: B -> A (512,30,40)
        dcconv((const int*)A,  DC[1], 1, (int*)Bb, nb);   // D2: A -> B (512,28,40)
        dcconv((const int*)Bb, DC[2], 2, (int*)A,  nb);   // D3: B -> A (512,26,40)
        {   // P4: A -> B (512,13,20)
            const int total = nb * 512 * 13 * 20;
            maxpool2_i32_k<<<(total + 255) / 256, 256, 0, stream>>>((int*)A, (int*)Bb, 512, 26, 40, 13, 20, total);
        }
        dcconv((const int*)Bb, DC[3], 3, (int*)A,  nb);   // D4: B -> A (512,11,22)
        dcconv((const int*)A,  DC[4], 4, (int*)Bb, nb);   // D5: A -> B (512,9,22)
        dcconv((const int*)Bb, DC[5], 5, (int*)A,  nb);   // D6: B -> A (512,7,22)
        {   // P5: A -> B (512,3,11)
            const int total = nb * 512 * 3 * 11;
            maxpool2_i32_k<<<(total + 255) / 256, 256, 0, stream>>>((int*)A, (int*)Bb, 512, 9, 22, 3, 11, total);
        }
        {   // mean pool: B -> P (nb,512)
            const int total = nb * 512;
            pool_mean_k<<<(total + 255) / 256, 256, 0, stream>>>((const int*)Bb, P, total);
        }
        {   // FC: P -> out rows n0..n0+nb-1
            const int total = nb * 1000;
            fc_k<<<(total + 255) / 256, 256, 0, stream>>>(P, fcw, fcb, outp, nb, n0);
        }
    }
}

// Round 2
// 19593.942 us; speedup vs baseline: 2.6252x; 2.6252x over previous
//
#include <hip/hip_runtime.h>

// ---------------------------------------------------------------------------
// VGG_DC round 2: all intermediates live in PRE-PADDED buffers (2-border for
// float convs pad=2, align-6 columns; width-pad only for DC valid convs).
// Producers self-zero their borders -> no memset, buffers ping-pong between
// two slabs per image. Conv kernels: compile-time shapes, immediate-offset
// loads, software-pipelined ci loop (register prefetch of next channel).
// Arithmetic order identical to round-1 passing run (bit-identical output).
// ---------------------------------------------------------------------------

#define TW 4
#define TCO 4

// ---- fp32 conv3x3 over pre-padded input --------------------------------
template<int CIN,int PH,int PW,int OH,int OW,int OPW,int COUT,bool BORDER>
__global__ __launch_bounds__(256) void convf_k(
    const float* __restrict__ in, const float* __restrict__ wgt,
    const float* __restrict__ bias, float* __restrict__ out, int nstr)
{
    constexpr int WB  = (OW + TW - 1) / TW;
    constexpr int CB  = COUT / TCO;
    constexpr int OPL = (BORDER ? OH + 4 : OH) * OPW;
    const int s = blockIdx.x * 256 + threadIdx.x;
    if (s >= OH * WB) return;
    const int w0 = (s % WB) * TW;
    const int h  = s / WB;
    const int n   = blockIdx.z / CB;
    const int co0 = (blockIdx.z % CB) * TCO;

    const float* ip = in + (size_t)n * nstr + (size_t)h * PW + w0;
    const float* wp = wgt + (size_t)co0 * CIN * 9;

    float acc[TCO][TW];
#pragma unroll
    for (int c = 0; c < TCO; ++c)
#pragma unroll
        for (int t = 0; t < TW; ++t) acc[c][t] = 0.f;

    // software pipeline: vb holds current ci's 3x(TW+2) window, vn prefetches
    float vb[3][TW + 2];
#pragma unroll
    for (int kh = 0; kh < 3; ++kh)
#pragma unroll
        for (int j = 0; j < TW + 2; ++j) vb[kh][j] = ip[kh * PW + j];

    for (int ci = 0; ci < CIN; ++ci) {
        ip += PH * PW;
        float vn[3][TW + 2];                  // prefetch ci+1 (overread of one
#pragma unroll                                // plane stays inside workspace)
        for (int kh = 0; kh < 3; ++kh)
#pragma unroll
            for (int j = 0; j < TW + 2; ++j) vn[kh][j] = ip[kh * PW + j];

#pragma unroll
        for (int kh = 0; kh < 3; ++kh) {
#pragma unroll
            for (int c = 0; c < TCO; ++c) {
                const float* wr = wp + ((size_t)c * CIN + ci) * 9 + kh * 3;
                const float k0 = wr[0], k1 = wr[1], k2 = wr[2];
#pragma unroll
                for (int t = 0; t < TW; ++t)
                    acc[c][t] = fmaf(vb[kh][t], k0,
                                fmaf(vb[kh][t + 1], k1,
                                fmaf(vb[kh][t + 2], k2, acc[c][t])));
            }
        }
#pragma unroll
        for (int kh = 0; kh < 3; ++kh)
#pragma unroll
            for (int j = 0; j < TW + 2; ++j) vb[kh][j] = vn[kh][j];
    }

    float* ob = out + (size_t)n * nstr;
    const int ph  = BORDER ? h + 2 : h;
    const int pwo = BORDER ? 2 : 0;
#pragma unroll
    for (int c = 0; c < TCO; ++c) {
        float* plane = ob + (size_t)(co0 + c) * OPL;
        float* row = plane + (size_t)ph * OPW;
        const float b = bias[co0 + c];
#pragma unroll
        for (int t = 0; t < TW; ++t)
            if (w0 + t < OW) { const float r = acc[c][t] + b; row[pwo + w0 + t] = r > 0.f ? r : 0.f; }
        if (BORDER) {
            if (w0 == 0) { row[0] = 0.f; row[1] = 0.f; }
            if (w0 + TW >= OW) {
#pragma unroll
                for (int pw = OW + 2; pw < OPW; ++pw) row[pw] = 0.f;
            }
            if (h == 0 || h == OH - 1) {           // also zero 2 border rows
                float* r0 = plane + (h == 0 ? 0 : (size_t)(OH + 2) * OPW);
#pragma unroll
                for (int rr = 0; rr < 2; ++rr) {
                    float* br = r0 + rr * OPW;
#pragma unroll
                    for (int t = 0; t < TW; ++t) if (w0 + t < OW) br[2 + w0 + t] = 0.f;
                    if (w0 == 0) { br[0] = 0.f; br[1] = 0.f; }
                    if (w0 + TW >= OW) {
#pragma unroll
                        for (int pw = OW + 2; pw < OPW; ++pw) br[pw] = 0.f;
                    }
                }
            }
        }
    }
}

// ---- int DC conv3x3 (valid) over width-padded input --------------------
template<int CIN,int PH,int PW,int OH,int OW,int OPW,int COUT>
__global__ __launch_bounds__(256) void convq_k(
    const int* __restrict__ in, const int* __restrict__ wgt,
    int* __restrict__ out, int nstr)
{
    constexpr int WB  = (OW + TW - 1) / TW;
    constexpr int CB  = COUT / TCO;
    constexpr int OPL = OH * OPW;
    const int s = blockIdx.x * 256 + threadIdx.x;
    if (s >= OH * WB) return;
    const int w0 = (s % WB) * TW;
    const int h  = s / WB;
    const int n   = blockIdx.z / CB;
    const int co0 = (blockIdx.z % CB) * TCO;

    const int* ip = in + (size_t)n * nstr + (size_t)h * PW + w0;
    const int* wp = wgt + (size_t)co0 * CIN * 9;

    int acc[TCO][TW];
#pragma unroll
    for (int c = 0; c < TCO; ++c)
#pragma unroll
        for (int t = 0; t < TW; ++t) acc[c][t] = 0;

    int vb[3][TW + 2];
#pragma unroll
    for (int kh = 0; kh < 3; ++kh)
#pragma unroll
        for (int j = 0; j < TW + 2; ++j) vb[kh][j] = ip[kh * PW + j];

    for (int ci = 0; ci < CIN; ++ci) {
        ip += PH * PW;
        int vn[3][TW + 2];
#pragma unroll
        for (int kh = 0; kh < 3; ++kh)
#pragma unroll
            for (int j = 0; j < TW + 2; ++j) vn[kh][j] = ip[kh * PW + j];

#pragma unroll
        for (int kh = 0; kh < 3; ++kh) {
            int v[TW + 2];
#pragma unroll
            for (int j = 0; j < TW + 2; ++j) v[j] = vb[kh][j] & 31;   // A_MASK
#pragma unroll
            for (int c = 0; c < TCO; ++c) {
                const int* wr = wp + ((size_t)c * CIN + ci) * 9 + kh * 3;
                const int k0 = wr[0] & 255, k1 = wr[1] & 255, k2 = wr[2] & 255;
#pragma unroll
                for (int t = 0; t < TW; ++t)
                    acc[c][t] += v[t] * k0 + v[t + 1] * k1 + v[t + 2] * k2;
            }
        }
#pragma unroll
        for (int kh = 0; kh < 3; ++kh)
#pragma unroll
            for (int j = 0; j < TW + 2; ++j) vb[kh][j] = vn[kh][j];
    }

    int* ob = out + (size_t)n * nstr;
#pragma unroll
    for (int c = 0; c < TCO; ++c) {
        int* row = ob + (size_t)(co0 + c) * OPL + (size_t)h * OPW;
#pragma unroll
        for (int t = 0; t < TW; ++t)
            if (w0 + t < OW) row[w0 + t] = acc[c][t];
        if (w0 + TW >= OW) {
#pragma unroll
            for (int pw = OW; pw < OPW; ++pw) row[pw] = 0;   // align-6 cols
        }
    }
}

// ---- maxpool 2x2/2 writing a full (possibly padded) dest plane ---------
template<int C,int HI,int WI,int HO,int WO,int OPH,int OPW,int OY,int OX,
         typename TI,typename TO>
__global__ void pool_k(const TI* __restrict__ in, TO* __restrict__ out,
                       int nstr, int total)
{
    const int i = blockIdx.x * 256 + threadIdx.x;
    if (i >= total) return;
    constexpr int OPL = OPH * OPW;
    int t = i;
    const int px = t % OPW; t /= OPW;
    const int py = t % OPH; t /= OPH;
    const int c  = t % C;   const int n = t / C;
    TO v = (TO)0;
    const int hy = py - OY, hx = px - OX;
    if (hy >= 0 && hy < HO && hx >= 0 && hx < WO) {
        const TI* p = in + (size_t)n * nstr + ((size_t)c * HI + 2 * hy) * WI + 2 * hx;
        TI m = p[0];
        m = m > p[1] ? m : p[1];
        m = m > p[WI] ? m : p[WI];
        m = m > p[WI + 1] ? m : p[WI + 1];
        v = (TO)m;                           // float->int truncates (m >= 0)
    }
    out[(size_t)n * nstr + (size_t)c * OPL + (size_t)py * OPW + px] = v;
}

// ---- copy x into padded (3,228,232) buffer -----------------------------
__global__ void copyin_k(const float* __restrict__ x, float* __restrict__ dst,
                         int nstr, int total)
{
    const int i = blockIdx.x * 256 + threadIdx.x;
    if (i >= total) return;
    int t = i;
    const int pw = t % 232; t /= 232;
    const int ph = t % 228; t /= 228;
    const int c  = t % 3;   const int n = t / 3;
    float v = 0.f;
    const int y = ph - 2, xx = pw - 2;
    if ((unsigned)y < 224u && (unsigned)xx < 224u)
        v = x[(size_t)n * 150528 + ((size_t)c * 224 + y) * 224 + xx];
    dst[(size_t)n * nstr + ((size_t)c * 228 + ph) * 232 + pw] = v;
}

// ---- head --------------------------------------------------------------
__global__ void pool_mean_k(const int* __restrict__ in, float* __restrict__ out,
                            int nstr, int total)
{
    const int i = blockIdx.x * 256 + threadIdx.x;
    if (i >= total) return;
    const int n = i / 512, c = i % 512;
    const int* p = in + (size_t)n * nstr + (size_t)c * 33;
    int s = 0;
#pragma unroll
    for (int j = 0; j < 33; ++j) s += p[j];
    out[(size_t)n * nstr + c] = (float)s / 33.0f;
}

__global__ void fc_k(const float* __restrict__ pooled, const float* __restrict__ w,
                     const float* __restrict__ b, float* __restrict__ out,
                     int nstr, int nb, int n0)
{
    const int i = blockIdx.x * 256 + threadIdx.x;
    if (i >= nb * 1000) return;
    const int co = i % 1000;
    const int n  = i / 1000;
    const float* pv = pooled + (size_t)n * nstr;
    const float* wr = w + (size_t)co * 512;
    float s = b[co];
    for (int c = 0; c < 512; ++c) s = fmaf(pv[c], wr[c], s);
    out[(size_t)(n0 + n) * 1000 + co] = s;
}

// ---------------------------------------------------------------------------
extern "C" void kernel_launch(void* const* d_in, const int* in_sizes, int n_in,
                              void* d_out, int out_size, void* d_ws, size_t ws_size,
                              hipStream_t stream)
{
    (void)n_in; (void)out_size;
    const float* x = (const float*)d_in[0];
    const float* W[7]; const float* Bv[7]; const int* Q[6];
    const bool inter = (in_sizes[2] == 64);
    for (int i = 0; i < 7; ++i) {
        if (inter) { W[i] = (const float*)d_in[1 + 2 * i]; Bv[i] = (const float*)d_in[2 + 2 * i]; }
        else       { W[i] = (const float*)d_in[1 + i];     Bv[i] = (const float*)d_in[8 + i];     }
    }
    for (int i = 0; i < 6; ++i) Q[i] = (const int*)d_in[15 + i];
    const float* fcw = (const float*)d_in[21];
    const float* fcb = (const float*)d_in[22];
    float* outp = (float*)d_out;

    // per-image slabs (elements): G0 = padded x, G1/G2 ping-pong
    constexpr size_t G0e = 0;
    constexpr size_t G1e = 634880 / 4;                       // 158,720 el
    constexpr size_t G2e = G1e + 3503680;                    // + F1 cap
    constexpr size_t PIBe = G2e + 3442432;                   // + F2 cap
    const int NSTR = (int)PIBe;                              // 7,104,832 el
    const size_t PIB = PIBe * 4;                             // 28,419,328 B

    int chunk = 16;
    while (chunk > 1 && (size_t)chunk * PIB > ws_size) chunk >>= 1;

    float* base = (float*)d_ws;
    float* X0 = base + G0e;
    float* B1 = base + G1e;          // slab 1
    float* B2 = base + G2e;          // slab 2

#define LCONVF(CIN,PH,PW,OH,OW,OPW,COUT,BRD,SRC,DST,WI) do {                     \
        constexpr int WB_ = (OW + TW - 1) / TW;                                  \
        const int gx = (OH * WB_ + 255) / 256;                                   \
        dim3 g(gx, 1, nb * (COUT / TCO));                                        \
        convf_k<CIN,PH,PW,OH,OW,OPW,COUT,BRD><<<g,256,0,stream>>>(               \
            SRC, W[WI], Bv[WI], DST, NSTR); } while (0)

#define LCONVQ(CIN,PH,PW,OH,OW,OPW,COUT,SRC,DST,QI) do {                         \
        constexpr int WB_ = (OW + TW - 1) / TW;                                  \
        const int gx = (OH * WB_ + 255) / 256;                                   \
        dim3 g(gx, 1, nb * (COUT / TCO));                                        \
        convq_k<CIN,PH,PW,OH,OW,OPW,COUT><<<g,256,0,stream>>>(                   \
            SRC, Q[QI], DST, NSTR); } while (0)

#define LPOOL(C,HI,WI,HO,WO,OPH,OPW,OY,OX,TI,TO,SRC,DST) do {                    \
        const int total = nb * C * OPH * OPW;                                    \
        pool_k<C,HI,WI,HO,WO,OPH,OPW,OY,OX,TI,TO>                                \
            <<<(total + 255) / 256, 256, 0, stream>>>(SRC, DST, NSTR, total);    \
    } while (0)

    for (int n0 = 0; n0 < 16; n0 += chunk) {
        const int nb = chunk;
        {   // x -> X0 (3,228,232) padded
            const int total = nb * 3 * 228 * 232;
            copyin_k<<<(total + 255) / 256, 256, 0, stream>>>(
                x + (size_t)n0 * 150528, X0, NSTR, total);
        }
        LCONVF(3,  228, 232, 226, 230, 238,  64, true,  X0, B1, 0);  // L1 -> F1@B1
        LCONVF(64, 230, 238, 228, 236, 236,  64, false, B1, B2, 1);  // L2 -> F2@B2 (raw)
        LPOOL (64, 228, 236, 114, 118, 118, 124, 2, 2, float, float, B2, B1);  // F3@B1
        LCONVF(64, 118, 124, 116, 122, 130, 128, true,  B1, B2, 2);  // L3 -> F4@B2
        LCONVF(128,120, 130, 118, 128, 128, 128, false, B2, B1, 3);  // L4 -> F5@B1 (raw)
        LPOOL (128,118, 128,  59,  64,  63,  70, 2, 2, float, float, B1, B2);  // F6@B2
        LCONVF(128, 63,  70,  61,  68,  76, 256, true,  B2, B1, 4);  // L5 -> F7@B1
        LCONVF(256, 65,  76,  63,  74,  82, 256, true,  B1, B2, 5);  // L6 -> F8@B2
        LCONVF(256, 67,  82,  65,  80,  80, 256, false, B2, B1, 6);  // L7 -> F9@B1 (raw)
        LPOOL (256, 65,  80,  32,  40,  32,  42, 0, 0, float, int, B1, (int*)B2); // I0@B2
        LCONVQ(256, 32,  42,  30,  40,  42, 512, (int*)B2, (int*)B1, 0);  // D1
        LCONVQ(512, 30,  42,  28,  40,  42, 512, (int*)B1, (int*)B2, 1);  // D2
        LCONVQ(512, 28,  42,  26,  40,  40, 512, (int*)B2, (int*)B1, 2);  // D3 (raw)
        LPOOL (512, 26,  40,  13,  20,  13,  24, 0, 0, int, int, (int*)B1, (int*)B2); // I4
        LCONVQ(512, 13,  24,  11,  22,  24, 512, (int*)B2, (int*)B1, 3);  // D4
        LCONVQ(512, 11,  24,   9,  22,  24, 512, (int*)B1, (int*)B2, 4);  // D5
        LCONVQ(512,  9,  24,   7,  22,  22, 512, (int*)B2, (int*)B1, 5);  // D6 (raw)
        LPOOL (512,  7,  22,   3,  11,   3,  11, 0, 0, int, int, (int*)B1, (int*)B2); // I8
        {   // mean over 33 -> P@B1
            const int total = nb * 512;
            pool_mean_k<<<(total + 255) / 256, 256, 0, stream>>>(
                (const int*)B2, B1, NSTR, total);
        }
        {   // FC
            const int total = nb * 1000;
            fc_k<<<(total + 255) / 256, 256, 0, stream>>>(
                B1, fcw, fcb, outp, NSTR, nb, n0);
        }
    }
#undef LCONVF
#undef LCONVQ
#undef LPOOL
}

// Round 3
// 7453.201 us; speedup vs baseline: 6.9016x; 2.6289x over previous
//
#include <hip/hip_runtime.h>

// ---------------------------------------------------------------------------
// VGG_DC round 3: pre-padded ping-pong slabs (as R2), plus:
//  - float convs use packed fp32 (v_pk_fma_f32 via v2f elementwise fma),
//    chain order preserved -> bit-identical to R2's passing run; TCO=8.
//  - DC convs use v_dot4_i32_i8 over channel-packed i8 activations/weights
//    (exact integer arithmetic; &31 applied at pack time).
// ---------------------------------------------------------------------------

#define TW 4        // outputs along W per thread (2 packed pairs)
#define TCOF 8      // float conv: output channels per thread
#define TCOQ 8      // dc conv: output channels per thread

typedef float v2f __attribute__((ext_vector_type(2)));

static __device__ inline int dot4(int a, int b, int c) {
#if __has_builtin(__builtin_amdgcn_sdot4)
    return __builtin_amdgcn_sdot4(a, b, c, false);
#else
    return c + (a & 255) * (b & 255)
             + ((a >> 8) & 255) * ((b >> 8) & 255)
             + ((a >> 16) & 255) * ((b >> 16) & 255)
             + ((a >> 24) & 255) * ((b >> 24) & 255);
#endif
}

// ---- fp32 conv3x3 over pre-padded input, packed-fp32 FMAs ----------------
template<int CIN,int PH,int PW,int OH,int OW,int OPW,int COUT,bool BORDER>
__global__ __launch_bounds__(256) void convf_k(
    const float* __restrict__ in, const float* __restrict__ wgt,
    const float* __restrict__ bias, float* __restrict__ out, int nstr)
{
    constexpr int WB  = (OW + TW - 1) / TW;
    constexpr int CB  = COUT / TCOF;
    constexpr int OPL = (BORDER ? OH + 4 : OH) * OPW;
    const int s = blockIdx.x * 256 + threadIdx.x;
    if (s >= OH * WB) return;
    const int w0 = (s % WB) * TW;
    const int h  = s / WB;
    const int n   = blockIdx.z / CB;
    const int co0 = (blockIdx.z % CB) * TCOF;

    const float* ip = in + (size_t)n * nstr + (size_t)h * PW + w0;
    const float* wp = wgt + (size_t)co0 * CIN * 9;

    v2f acc[TCOF][2];
#pragma unroll
    for (int c = 0; c < TCOF; ++c) { acc[c][0] = (v2f)0.f; acc[c][1] = (v2f)0.f; }

    float vb[3][TW + 2];
#pragma unroll
    for (int kh = 0; kh < 3; ++kh)
#pragma unroll
        for (int j = 0; j < TW + 2; ++j) vb[kh][j] = ip[kh * PW + j];

#pragma unroll 2
    for (int ci = 0; ci < CIN; ++ci) {
        ip += PH * PW;
        float vn[3][TW + 2];
#pragma unroll
        for (int kh = 0; kh < 3; ++kh)
#pragma unroll
            for (int j = 0; j < TW + 2; ++j) vn[kh][j] = ip[kh * PW + j];

#pragma unroll
        for (int kh = 0; kh < 3; ++kh) {
            // register pairs over consecutive w positions
            const v2f P0 = {vb[kh][0], vb[kh][1]};
            const v2f P1 = {vb[kh][1], vb[kh][2]};
            const v2f P2 = {vb[kh][2], vb[kh][3]};
            const v2f Q1 = {vb[kh][3], vb[kh][4]};
            const v2f Q2 = {vb[kh][4], vb[kh][5]};
#pragma unroll
            for (int c = 0; c < TCOF; ++c) {
                const float* wr = wp + ((size_t)c * CIN + ci) * 9 + kh * 3;
                const float k0 = wr[0], k1 = wr[1], k2 = wr[2];
                const v2f k0p = {k0, k0}, k1p = {k1, k1}, k2p = {k2, k2};
                // chain order k2 -> k1 -> k0 == fmaf(v0,k0,fmaf(v1,k1,fmaf(v2,k2,acc)))
                v2f a0 = acc[c][0];
                a0 = __builtin_elementwise_fma(P2, k2p, a0);
                a0 = __builtin_elementwise_fma(P1, k1p, a0);
                a0 = __builtin_elementwise_fma(P0, k0p, a0);
                acc[c][0] = a0;
                v2f a1 = acc[c][1];
                a1 = __builtin_elementwise_fma(Q2, k2p, a1);
                a1 = __builtin_elementwise_fma(Q1, k1p, a1);
                a1 = __builtin_elementwise_fma(P2, k0p, a1);
                acc[c][1] = a1;
            }
        }
#pragma unroll
        for (int kh = 0; kh < 3; ++kh)
#pragma unroll
            for (int j = 0; j < TW + 2; ++j) vb[kh][j] = vn[kh][j];
    }

    float* ob = out + (size_t)n * nstr;
    const int ph  = BORDER ? h + 2 : h;
    const int pwo = BORDER ? 2 : 0;
#pragma unroll
    for (int c = 0; c < TCOF; ++c) {
        float* plane = ob + (size_t)(co0 + c) * OPL;
        float* row = plane + (size_t)ph * OPW;
        const float b = bias[co0 + c];
        float av[TW] = {acc[c][0][0], acc[c][0][1], acc[c][1][0], acc[c][1][1]};
#pragma unroll
        for (int t = 0; t < TW; ++t)
            if (w0 + t < OW) { const float r = av[t] + b; row[pwo + w0 + t] = r > 0.f ? r : 0.f; }
        if (BORDER) {
            if (w0 == 0) { row[0] = 0.f; row[1] = 0.f; }
            if (w0 + TW >= OW) {
#pragma unroll
                for (int pw = OW + 2; pw < OPW; ++pw) row[pw] = 0.f;
            }
            if (h == 0 || h == OH - 1) {
                float* r0 = plane + (h == 0 ? 0 : (size_t)(OH + 2) * OPW);
#pragma unroll
                for (int rr = 0; rr < 2; ++rr) {
                    float* br = r0 + rr * OPW;
#pragma unroll
                    for (int t = 0; t < TW; ++t) if (w0 + t < OW) br[2 + w0 + t] = 0.f;
                    if (w0 == 0) { br[0] = 0.f; br[1] = 0.f; }
                    if (w0 + TW >= OW) {
#pragma unroll
                        for (int pw = OW + 2; pw < OPW; ++pw) br[pw] = 0.f;
                    }
                }
            }
        }
    }
}

// ---- int DC conv3x3 (valid) with i8x4 packed channels + dot4 -------------
template<int CIN4,int PH,int PW,int OH,int OW,int OPW,int COUT>
__global__ __launch_bounds__(256) void convq4_k(
    const int* __restrict__ in, const int* __restrict__ wq,
    int* __restrict__ out, int nstr)
{
    constexpr int WB  = (OW + TW - 1) / TW;
    constexpr int CB  = COUT / TCOQ;
    constexpr int OPL = OH * OPW;
    const int s = blockIdx.x * 256 + threadIdx.x;
    if (s >= OH * WB) return;
    const int w0 = (s % WB) * TW;
    const int h  = s / WB;
    const int n   = blockIdx.z / CB;
    const int co0 = (blockIdx.z % CB) * TCOQ;

    const int* ip = in + (size_t)n * nstr + (size_t)h * PW + w0;
    const int* wp = wq + (size_t)co0 * CIN4 * 9;

    int acc[TCOQ][TW];
#pragma unroll
    for (int c = 0; c < TCOQ; ++c)
#pragma unroll
        for (int t = 0; t < TW; ++t) acc[c][t] = 0;

    int vb[3][TW + 2];
#pragma unroll
    for (int kh = 0; kh < 3; ++kh)
#pragma unroll
        for (int j = 0; j < TW + 2; ++j) vb[kh][j] = ip[kh * PW + j];

#pragma unroll 2
    for (int ci = 0; ci < CIN4; ++ci) {
        ip += PH * PW;
        int vn[3][TW + 2];
#pragma unroll
        for (int kh = 0; kh < 3; ++kh)
#pragma unroll
            for (int j = 0; j < TW + 2; ++j) vn[kh][j] = ip[kh * PW + j];

#pragma unroll
        for (int kh = 0; kh < 3; ++kh) {
#pragma unroll
            for (int c = 0; c < TCOQ; ++c) {
                const int* wr = wp + ((size_t)c * CIN4 + ci) * 9 + kh * 3;
                const int k0 = wr[0], k1 = wr[1], k2 = wr[2];
#pragma unroll
                for (int t = 0; t < TW; ++t)
                    acc[c][t] = dot4(vb[kh][t], k0,
                                dot4(vb[kh][t + 1], k1,
                                dot4(vb[kh][t + 2], k2, acc[c][t])));
            }
        }
#pragma unroll
        for (int kh = 0; kh < 3; ++kh)
#pragma unroll
            for (int j = 0; j < TW + 2; ++j) vb[kh][j] = vn[kh][j];
    }

    int* ob = out + (size_t)n * nstr;
#pragma unroll
    for (int c = 0; c < TCOQ; ++c) {
        int* row = ob + (size_t)(co0 + c) * OPL + (size_t)h * OPW;
#pragma unroll
        for (int t = 0; t < TW; ++t)
            if (w0 + t < OW) row[w0 + t] = acc[c][t];
        if (w0 + TW >= OW) {
#pragma unroll
            for (int pw = OW; pw < OPW; ++pw) row[pw] = 0;
        }
    }
}

// ---- pack DC weights: (co,ci,3,3) i32 -> [co][ci/4][9] i8x4 --------------
__global__ void pack_w_k(const int* __restrict__ q, int* __restrict__ out,
                         int CIN4, int total)
{
    const int i = blockIdx.x * 256 + threadIdx.x;
    if (i >= total) return;
    const int r = i % 9;
    int t = i / 9;
    const int ci4 = t % CIN4;
    const int co  = t / CIN4;
    const int CIN = CIN4 * 4;
    const int* p = q + ((size_t)co * CIN + ci4 * 4) * 9 + r;
    out[i] = (p[0] & 255) | ((p[9] & 255) << 8) | ((p[18] & 255) << 16) | ((p[27] & 255) << 24);
}

// ---- pack DC activations: [ci][h][w] i32 raw -> [ci/4][h][w] i8x4 (&31) --
template<int CIN, int PH, int PW>
__global__ void pack_a_k(const int* __restrict__ in, int* __restrict__ out,
                         int nstr, int total)
{
    const int i = blockIdx.x * 256 + threadIdx.x;
    if (i >= total) return;
    constexpr int CIN4 = CIN / 4;
    constexpr int PL = PH * PW;
    int t = i;
    const int pw = t % PW; t /= PW;
    const int ph = t % PH; t /= PH;
    const int c4 = t % CIN4; const int n = t / CIN4;
    const int* p = in + (size_t)n * nstr + ((size_t)(c4 * 4) * PH + ph) * PW + pw;
    const int w = (p[0] & 31) | ((p[PL] & 31) << 8) | ((p[2 * PL] & 31) << 16) | ((p[3 * PL] & 31) << 24);
    out[(size_t)n * nstr + ((size_t)c4 * PH + ph) * PW + pw] = w;
}

// ---- maxpool 2x2/2 writing a full (possibly padded) dest plane -----------
template<int C,int HI,int WI,int HO,int WO,int OPH,int OPW,int OY,int OX,
         typename TI,typename TO>
__global__ void pool_k(const TI* __restrict__ in, TO* __restrict__ out,
                       int nstr, int total)
{
    const int i = blockIdx.x * 256 + threadIdx.x;
    if (i >= total) return;
    constexpr int OPL = OPH * OPW;
    int t = i;
    const int px = t % OPW; t /= OPW;
    const int py = t % OPH; t /= OPH;
    const int c  = t % C;   const int n = t / C;
    TO v = (TO)0;
    const int hy = py - OY, hx = px - OX;
    if (hy >= 0 && hy < HO && hx >= 0 && hx < WO) {
        const TI* p = in + (size_t)n * nstr + ((size_t)c * HI + 2 * hy) * WI + 2 * hx;
        TI m = p[0];
        m = m > p[1] ? m : p[1];
        m = m > p[WI] ? m : p[WI];
        m = m > p[WI + 1] ? m : p[WI + 1];
        v = (TO)m;
    }
    out[(size_t)n * nstr + (size_t)c * OPL + (size_t)py * OPW + px] = v;
}

// ---- copy x into padded (3,228,232) buffer -------------------------------
__global__ void copyin_k(const float* __restrict__ x, float* __restrict__ dst,
                         int nstr, int total)
{
    const int i = blockIdx.x * 256 + threadIdx.x;
    if (i >= total) return;
    int t = i;
    const int pw = t % 232; t /= 232;
    const int ph = t % 228; t /= 228;
    const int c  = t % 3;   const int n = t / 3;
    float v = 0.f;
    const int y = ph - 2, xx = pw - 2;
    if ((unsigned)y < 224u && (unsigned)xx < 224u)
        v = x[(size_t)n * 150528 + ((size_t)c * 224 + y) * 224 + xx];
    dst[(size_t)n * nstr + ((size_t)c * 228 + ph) * 232 + pw] = v;
}

// ---- head ----------------------------------------------------------------
__global__ void pool_mean_k(const int* __restrict__ in, float* __restrict__ out,
                            int nstr, int total)
{
    const int i = blockIdx.x * 256 + threadIdx.x;
    if (i >= total) return;
    const int n = i / 512, c = i % 512;
    const int* p = in + (size_t)n * nstr + (size_t)c * 33;
    int s = 0;
#pragma unroll
    for (int j = 0; j < 33; ++j) s += p[j];
    out[(size_t)n * nstr + c] = (float)s / 33.0f;
}

__global__ void fc_k(const float* __restrict__ pooled, const float* __restrict__ w,
                     const float* __restrict__ b, float* __restrict__ out,
                     int nstr, int nb, int n0)
{
    const int i = blockIdx.x * 256 + threadIdx.x;
    if (i >= nb * 1000) return;
    const int co = i % 1000;
    const int n  = i / 1000;
    const float* pv = pooled + (size_t)n * nstr;
    const float* wr = w + (size_t)co * 512;
    float s = b[co];
    for (int c = 0; c < 512; ++c) s = fmaf(pv[c], wr[c], s);
    out[(size_t)(n0 + n) * 1000 + co] = s;
}

// ---------------------------------------------------------------------------
extern "C" void kernel_launch(void* const* d_in, const int* in_sizes, int n_in,
                              void* d_out, int out_size, void* d_ws, size_t ws_size,
                              hipStream_t stream)
{
    (void)n_in; (void)out_size;
    const float* x = (const float*)d_in[0];
    const float* W[7]; const float* Bv[7]; const int* Q[6];
    const bool inter = (in_sizes[2] == 64);
    for (int i = 0; i < 7; ++i) {
        if (inter) { W[i] = (const float*)d_in[1 + 2 * i]; Bv[i] = (const float*)d_in[2 + 2 * i]; }
        else       { W[i] = (const float*)d_in[1 + i];     Bv[i] = (const float*)d_in[8 + i];     }
    }
    for (int i = 0; i < 6; ++i) Q[i] = (const int*)d_in[15 + i];
    const float* fcw = (const float*)d_in[21];
    const float* fcb = (const float*)d_in[22];
    float* outp = (float*)d_out;

    // packed DC weights at workspace start: [co][ci/4][9]
    static const int QCO[6]  = {512, 512, 512, 512, 512, 512};
    static const int QCIN[6] = {256, 512, 512, 512, 512, 512};
    size_t wqoff[6]; size_t wqtot = 0;
    for (int i = 0; i < 6; ++i) { wqoff[i] = wqtot; wqtot += (size_t)QCO[i] * (QCIN[i] / 4) * 9; }

    int* wqbase = (int*)d_ws;
    for (int i = 0; i < 6; ++i) {
        const int total = QCO[i] * (QCIN[i] / 4) * 9;
        pack_w_k<<<(total + 255) / 256, 256, 0, stream>>>(Q[i], wqbase + wqoff[i], QCIN[i] / 4, total);
    }

    // per-image slabs (elements)
    constexpr size_t G0e = 0;
    constexpr size_t G1e = 158720;                 // padded x cap
    constexpr size_t G2e = G1e + 3503680;          // + slab1 cap
    constexpr size_t PKe = G2e + 3442432;          // + slab2 cap
    constexpr size_t PIBe = PKe + 161280 + 2048;   // + packed-act cap + guard
    const int NSTR = (int)PIBe;
    const size_t PIB = PIBe * 4;

    int chunk = 16;
    while (chunk > 1 && (wqtot * 4 + (size_t)chunk * PIB) > ws_size) chunk >>= 1;

    float* base = (float*)(wqbase + wqtot);
    float* X0 = base + G0e;
    float* B1 = base + G1e;
    float* B2 = base + G2e;
    int*   PK = (int*)(base + PKe);

#define LCONVF(CIN,PH,PW,OH,OW,OPW,COUT,BRD,SRC,DST,WI) do {                     \
        constexpr int WB_ = (OW + TW - 1) / TW;                                  \
        const int gx = (OH * WB_ + 255) / 256;                                   \
        dim3 g(gx, 1, nb * (COUT / TCOF));                                       \
        convf_k<CIN,PH,PW,OH,OW,OPW,COUT,BRD><<<g,256,0,stream>>>(               \
            SRC, W[WI], Bv[WI], DST, NSTR); } while (0)

#define LPACKA(CIN,PH,PW,SRC) do {                                               \
        const int total = nb * (CIN / 4) * PH * PW;                              \
        pack_a_k<CIN,PH,PW><<<(total + 255) / 256, 256, 0, stream>>>(            \
            (const int*)(SRC), PK, NSTR, total); } while (0)

#define LCONVQ(CIN,PH,PW,OH,OW,OPW,COUT,DST,QI) do {                             \
        constexpr int WB_ = (OW + TW - 1) / TW;                                  \
        const int gx = (OH * WB_ + 255) / 256;                                   \
        dim3 g(gx, 1, nb * (COUT / TCOQ));                                       \
        convq4_k<(CIN)/4,PH,PW,OH,OW,OPW,COUT><<<g,256,0,stream>>>(              \
            PK, wqbase + wqoff[QI], (int*)(DST), NSTR); } while (0)

#define LPOOL(C,HI,WI,HO,WO,OPH,OPW,OY,OX,TI,TO,SRC,DST) do {                    \
        const int total = nb * C * OPH * OPW;                                    \
        pool_k<C,HI,WI,HO,WO,OPH,OPW,OY,OX,TI,TO>                                \
            <<<(total + 255) / 256, 256, 0, stream>>>(SRC, DST, NSTR, total);    \
    } while (0)

    for (int n0 = 0; n0 < 16; n0 += chunk) {
        const int nb = chunk;
        {   // x -> X0 (3,228,232) padded
            const int total = nb * 3 * 228 * 232;
            copyin_k<<<(total + 255) / 256, 256, 0, stream>>>(
                x + (size_t)n0 * 150528, X0, NSTR, total);
        }
        LCONVF(3,  228, 232, 226, 230, 238,  64, true,  X0, B1, 0);  // L1
        LCONVF(64, 230, 238, 228, 236, 236,  64, false, B1, B2, 1);  // L2 (raw)
        LPOOL (64, 228, 236, 114, 118, 118, 124, 2, 2, float, float, B2, B1);
        LCONVF(64, 118, 124, 116, 122, 130, 128, true,  B1, B2, 2);  // L3
        LCONVF(128,120, 130, 118, 128, 128, 128, false, B2, B1, 3);  // L4 (raw)
        LPOOL (128,118, 128,  59,  64,  63,  70, 2, 2, float, float, B1, B2);
        LCONVF(128, 63,  70,  61,  68,  76, 256, true,  B2, B1, 4);  // L5
        LCONVF(256, 65,  76,  63,  74,  82, 256, true,  B1, B2, 5);  // L6
        LCONVF(256, 67,  82,  65,  80,  80, 256, false, B2, B1, 6);  // L7 (raw)
        LPOOL (256, 65,  80,  32,  40,  32,  42, 0, 0, float, int, B1, (int*)B2); // I0
        LPACKA(256, 32, 42, B2);  LCONVQ(256, 32, 42, 30, 40, 42, 512, B1, 0);  // D1
        LPACKA(512, 30, 42, B1);  LCONVQ(512, 30, 42, 28, 40, 42, 512, B2, 1);  // D2
        LPACKA(512, 28, 42, B2);  LCONVQ(512, 28, 42, 26, 40, 40, 512, B1, 2);  // D3 (raw)
        LPOOL (512, 26, 40, 13, 20, 13, 24, 0, 0, int, int, (int*)B1, (int*)B2); // I4
        LPACKA(512, 13, 24, B2);  LCONVQ(512, 13, 24, 11, 22, 24, 512, B1, 3);  // D4
        LPACKA(512, 11, 24, B1);  LCONVQ(512, 11, 24,  9, 22, 24, 512, B2, 4);  // D5
        LPACKA(512,  9, 24, B2);  LCONVQ(512,  9, 24,  7, 22, 22, 512, B1, 5);  // D6 (raw)
        LPOOL (512,  7, 22,  3, 11,  3, 11, 0, 0, int, int, (int*)B1, (int*)B2); // I8
        {   // mean over 33 -> P@B1
            const int total = nb * 512;
            pool_mean_k<<<(total + 255) / 256, 256, 0, stream>>>(
                (const int*)B2, B1, NSTR, total);
        }
        {   // FC
            const int total = nb * 1000;
            fc_k<<<(total + 255) / 256, 256, 0, stream>>>(
                B1, fcw, fcb, outp, NSTR, nb, n0);
        }
    }
#undef LCONVF
#undef LPACKA
#undef LCONVQ
#undef LPOOL
}

// Round 4
// 6184.797 us; speedup vs baseline: 8.3170x; 1.2051x over previous
//
#include <hip/hip_runtime.h>
#include <cstddef>

// ---------------------------------------------------------------------------
// VGG_DC round 4: fused conv+maxpool (L2,L4,L7), full-batch-16 stage B,
// mult-of-4 padded widths (float4/float2 + int4/int2 loads), packed weights,
// DC convs emit pre-packed i8x4 activations. Arithmetic chains identical to
// R2/R3 passing runs -> bit-identical output.
// ---------------------------------------------------------------------------

typedef float v2f __attribute__((ext_vector_type(2)));

static __device__ __forceinline__ int dot4(int a, int b, int c) {
#if __has_builtin(__builtin_amdgcn_sdot4)
    return __builtin_amdgcn_sdot4(a, b, c, false);
#else
    return c + (a & 255) * (b & 255)
             + ((a >> 8) & 255) * ((b >> 8) & 255)
             + ((a >> 16) & 255) * ((b >> 16) & 255)
             + ((a >> 24) & 255) * ((b >> 24) & 255);
#endif
}

static __device__ __forceinline__ void ld6f(const float* __restrict__ p, float v[6]) {
    const float4 a = *reinterpret_cast<const float4*>(p);
    const float2 b = *reinterpret_cast<const float2*>(p + 4);
    v[0] = a.x; v[1] = a.y; v[2] = a.z; v[3] = a.w; v[4] = b.x; v[5] = b.y;
}
static __device__ __forceinline__ void ld6i(const int* __restrict__ p, int v[6]) {
    const int4 a = *reinterpret_cast<const int4*>(p);
    const int2 b = *reinterpret_cast<const int2*>(p + 4);
    v[0] = a.x; v[1] = a.y; v[2] = a.z; v[3] = a.w; v[4] = b.x; v[5] = b.y;
}

// ---- plain fp32 conv3x3 (pre-padded in/out), TCOF=8 ----------------------
template<int CIN,int PH,int PW,int OH,int OW,int OPW,bool BORDER>
__global__ __launch_bounds__(256) void convf_k(
    const float* __restrict__ in, int instr,
    const float* __restrict__ wfp, const float* __restrict__ bias,
    float* __restrict__ out, int outstr, int total)
{
    constexpr int WB  = (OW + 3) / 4;
    constexpr int OPH = BORDER ? OH + 4 : OH;
    constexpr int OPL = OPH * OPW;
    const int s = blockIdx.x * 256 + threadIdx.x;
    if (s >= total) return;
    const int wb = s % WB;
    const int h  = (s / WB) % OH;
    const int n  = s / (WB * OH);
    const int w0 = wb * 4;
    const int cob = blockIdx.z;
    const int co0 = cob * 8;

    const float* ip = in + (size_t)n * instr + (size_t)h * PW + w0;
    const float* wl = wfp + (size_t)cob * CIN * 72;

    v2f acc[8][2];
#pragma unroll
    for (int c = 0; c < 8; ++c) { acc[c][0] = (v2f)0.f; acc[c][1] = (v2f)0.f; }

    float vb[3][6];
#pragma unroll
    for (int kh = 0; kh < 3; ++kh) ld6f(ip + kh * PW, vb[kh]);

#pragma unroll 2
    for (int ci = 0; ci < CIN; ++ci) {
        ip += PH * PW;
        float vn[3][6];
#pragma unroll
        for (int kh = 0; kh < 3; ++kh) ld6f(ip + kh * PW, vn[kh]);
        const float* wr = wl + ci * 72;
#pragma unroll
        for (int kh = 0; kh < 3; ++kh) {
            const v2f P0 = {vb[kh][0], vb[kh][1]};
            const v2f P1 = {vb[kh][1], vb[kh][2]};
            const v2f P2 = {vb[kh][2], vb[kh][3]};
            const v2f Q1 = {vb[kh][3], vb[kh][4]};
            const v2f Q2 = {vb[kh][4], vb[kh][5]};
#pragma unroll
            for (int c = 0; c < 8; ++c) {
                const float k0 = wr[c * 9 + kh * 3 + 0];
                const float k1 = wr[c * 9 + kh * 3 + 1];
                const float k2 = wr[c * 9 + kh * 3 + 2];
                const v2f k0p = {k0, k0}, k1p = {k1, k1}, k2p = {k2, k2};
                v2f a0 = acc[c][0];
                a0 = __builtin_elementwise_fma(P2, k2p, a0);
                a0 = __builtin_elementwise_fma(P1, k1p, a0);
                a0 = __builtin_elementwise_fma(P0, k0p, a0);
                acc[c][0] = a0;
                v2f a1 = acc[c][1];
                a1 = __builtin_elementwise_fma(Q2, k2p, a1);
                a1 = __builtin_elementwise_fma(Q1, k1p, a1);
                a1 = __builtin_elementwise_fma(P2, k0p, a1);
                acc[c][1] = a1;
            }
        }
#pragma unroll
        for (int kh = 0; kh < 3; ++kh)
#pragma unroll
            for (int j = 0; j < 6; ++j) vb[kh][j] = vn[kh][j];
    }

    float* ob = out + (size_t)n * outstr;
    const int ph  = BORDER ? h + 2 : h;
    const int pwo = BORDER ? 2 : 0;
#pragma unroll
    for (int c = 0; c < 8; ++c) {
        float* plane = ob + (size_t)(co0 + c) * OPL;
        float* row = plane + (size_t)ph * OPW;
        const float b = bias[co0 + c];
        float av[4] = {acc[c][0][0], acc[c][0][1], acc[c][1][0], acc[c][1][1]};
#pragma unroll
        for (int t = 0; t < 4; ++t)
            if (w0 + t < OW) { const float r = av[t] + b; row[pwo + w0 + t] = r > 0.f ? r : 0.f; }
        if (BORDER) {
            if (wb == 0) { row[0] = 0.f; row[1] = 0.f; }
            if (wb == WB - 1) { for (int pw = OW + 2; pw < OPW; ++pw) row[pw] = 0.f; }
            if (h == 0 || h == OH - 1) {
                float* r0 = plane + (h == 0 ? 0 : (size_t)(OH + 2) * OPW);
                for (int rr = 0; rr < 2; ++rr) {
                    float* br = r0 + (size_t)rr * OPW;
#pragma unroll
                    for (int t = 0; t < 4; ++t) if (w0 + t < OW) br[2 + w0 + t] = 0.f;
                    if (wb == 0) { br[0] = 0.f; br[1] = 0.f; }
                    if (wb == WB - 1) { for (int pw = OW + 2; pw < OPW; ++pw) br[pw] = 0.f; }
                }
            }
        }
    }
}

// ---- fused fp32 conv3x3 + relu + maxpool2 (+optional int cast), TCOF=4 ---
template<int CIN,int PH,int PW,int POH,int POW,int OPW,int OY,int OX,bool TOINT>
__global__ __launch_bounds__(256) void convfp_k(
    const float* __restrict__ in, int instr,
    const float* __restrict__ wfp, const float* __restrict__ bias,
    void* __restrict__ outv, int outstr, int total)
{
    constexpr int WBp = POW / 2;
    constexpr int OPH = POH + 2 * OY;
    constexpr int OPL = OPH * OPW;
    const int s = blockIdx.x * 256 + threadIdx.x;
    if (s >= total) return;
    const int pb = s % WBp;
    const int ph = (s / WBp) % POH;
    const int n  = s / (WBp * POH);
    const int cob = blockIdx.z;
    const int co0 = cob * 4;

    const float* ip = in + (size_t)n * instr + (size_t)(2 * ph) * PW + 4 * pb;
    const float* wl = wfp + (size_t)cob * CIN * 36;

    v2f acc[4][2][2];
#pragma unroll
    for (int c = 0; c < 4; ++c)
#pragma unroll
        for (int r = 0; r < 2; ++r) { acc[c][r][0] = (v2f)0.f; acc[c][r][1] = (v2f)0.f; }

    float vb[4][6];
#pragma unroll
    for (int r = 0; r < 4; ++r) ld6f(ip + r * PW, vb[r]);

    for (int ci = 0; ci < CIN; ++ci) {
        ip += PH * PW;
        float vn[4][6];
#pragma unroll
        for (int r = 0; r < 4; ++r) ld6f(ip + r * PW, vn[r]);
        const float* wr = wl + ci * 36;
#pragma unroll
        for (int r = 0; r < 2; ++r) {
#pragma unroll
            for (int kh = 0; kh < 3; ++kh) {
                const float* vv = vb[r + kh];
                const v2f P0 = {vv[0], vv[1]};
                const v2f P1 = {vv[1], vv[2]};
                const v2f P2 = {vv[2], vv[3]};
                const v2f Q1 = {vv[3], vv[4]};
                const v2f Q2 = {vv[4], vv[5]};
#pragma unroll
                for (int c = 0; c < 4; ++c) {
                    const float k0 = wr[c * 9 + kh * 3 + 0];
                    const float k1 = wr[c * 9 + kh * 3 + 1];
                    const float k2 = wr[c * 9 + kh * 3 + 2];
                    const v2f k0p = {k0, k0}, k1p = {k1, k1}, k2p = {k2, k2};
                    v2f a0 = acc[c][r][0];
                    a0 = __builtin_elementwise_fma(P2, k2p, a0);
                    a0 = __builtin_elementwise_fma(P1, k1p, a0);
                    a0 = __builtin_elementwise_fma(P0, k0p, a0);
                    acc[c][r][0] = a0;
                    v2f a1 = acc[c][r][1];
                    a1 = __builtin_elementwise_fma(Q2, k2p, a1);
                    a1 = __builtin_elementwise_fma(Q1, k1p, a1);
                    a1 = __builtin_elementwise_fma(P2, k0p, a1);
                    acc[c][r][1] = a1;
                }
            }
        }
#pragma unroll
        for (int r = 0; r < 4; ++r)
#pragma unroll
            for (int j = 0; j < 6; ++j) vb[r][j] = vn[r][j];
    }

#pragma unroll
    for (int c = 0; c < 4; ++c) {
        const float b = bias[co0 + c];
        float r00 = acc[c][0][0][0] + b; r00 = r00 > 0.f ? r00 : 0.f;
        float r01 = acc[c][0][0][1] + b; r01 = r01 > 0.f ? r01 : 0.f;
        float r02 = acc[c][0][1][0] + b; r02 = r02 > 0.f ? r02 : 0.f;
        float r03 = acc[c][0][1][1] + b; r03 = r03 > 0.f ? r03 : 0.f;
        float r10 = acc[c][1][0][0] + b; r10 = r10 > 0.f ? r10 : 0.f;
        float r11 = acc[c][1][0][1] + b; r11 = r11 > 0.f ? r11 : 0.f;
        float r12 = acc[c][1][1][0] + b; r12 = r12 > 0.f ? r12 : 0.f;
        float r13 = acc[c][1][1][1] + b; r13 = r13 > 0.f ? r13 : 0.f;
        float p0 = r00; p0 = p0 > r01 ? p0 : r01; p0 = p0 > r10 ? p0 : r10; p0 = p0 > r11 ? p0 : r11;
        float p1 = r02; p1 = p1 > r03 ? p1 : r03; p1 = p1 > r12 ? p1 : r12; p1 = p1 > r13 ? p1 : r13;

        if constexpr (TOINT) {
            int* plane = (int*)outv + (size_t)n * outstr + (size_t)(co0 + c) * OPL;
            int* row = plane + (size_t)(OY + ph) * OPW;
            row[OX + 2 * pb]     = (int)p0;
            row[OX + 2 * pb + 1] = (int)p1;
            if (pb == WBp - 1) { for (int pw = OX + POW; pw < OPW; ++pw) row[pw] = 0; }
        } else {
            float* plane = (float*)outv + (size_t)n * outstr + (size_t)(co0 + c) * OPL;
            float* row = plane + (size_t)(OY + ph) * OPW;
            row[OX + 2 * pb]     = p0;
            row[OX + 2 * pb + 1] = p1;
            if (OX > 0 && pb == 0) { row[0] = 0.f; row[1] = 0.f; }
            if (pb == WBp - 1) { for (int pw = OX + POW; pw < OPW; ++pw) row[pw] = 0.f; }
            if (OY > 0 && (ph == 0 || ph == POH - 1)) {
                float* r0 = plane + (ph == 0 ? 0 : (size_t)(OY + POH) * OPW);
                for (int rr = 0; rr < OY; ++rr) {
                    float* br = r0 + (size_t)rr * OPW;
                    br[OX + 2 * pb] = 0.f; br[OX + 2 * pb + 1] = 0.f;
                    if (pb == 0) { br[0] = 0.f; br[1] = 0.f; }
                    if (pb == WBp - 1) { for (int pw = OX + POW; pw < OPW; ++pw) br[pw] = 0.f; }
                }
            }
        }
    }
}

// ---- int DC conv3x3 (valid) on i8x4-packed input, TCOQ=8 ----------------
template<int CIN4,int PH,int PW,int OH,int OW,int OPW,bool PACKOUT>
__global__ __launch_bounds__(256) void convq_k(
    const int* __restrict__ in, int instr, const int* __restrict__ wqp,
    int* __restrict__ out, int outstr, int total)
{
    constexpr int WB  = (OW + 3) / 4;
    constexpr int OPL = OH * OPW;
    const int s = blockIdx.x * 256 + threadIdx.x;
    if (s >= total) return;
    const int wb = s % WB;
    const int h  = (s / WB) % OH;
    const int n  = s / (WB * OH);
    const int w0 = wb * 4;
    const int cob = blockIdx.z;       // COUT/8
    const int co0 = cob * 8;

    const int* ip = in + (size_t)n * instr + (size_t)h * PW + w0;
    const int* wl = wqp + (size_t)cob * CIN4 * 72;

    int acc[8][4];
#pragma unroll
    for (int c = 0; c < 8; ++c)
#pragma unroll
        for (int t = 0; t < 4; ++t) acc[c][t] = 0;

    int vb[3][6];
#pragma unroll
    for (int kh = 0; kh < 3; ++kh) ld6i(ip + kh * PW, vb[kh]);

#pragma unroll 2
    for (int ci = 0; ci < CIN4; ++ci) {
        ip += PH * PW;
        int vn[3][6];
#pragma unroll
        for (int kh = 0; kh < 3; ++kh) ld6i(ip + kh * PW, vn[kh]);
        const int* wr = wl + ci * 72;
#pragma unroll
        for (int kh = 0; kh < 3; ++kh) {
#pragma unroll
            for (int c = 0; c < 8; ++c) {
                const int k0 = wr[c * 9 + kh * 3 + 0];
                const int k1 = wr[c * 9 + kh * 3 + 1];
                const int k2 = wr[c * 9 + kh * 3 + 2];
#pragma unroll
                for (int t = 0; t < 4; ++t)
                    acc[c][t] = dot4(vb[kh][t], k0,
                                dot4(vb[kh][t + 1], k1,
                                dot4(vb[kh][t + 2], k2, acc[c][t])));
            }
        }
#pragma unroll
        for (int kh = 0; kh < 3; ++kh)
#pragma unroll
            for (int j = 0; j < 6; ++j) vb[kh][j] = vn[kh][j];
    }

    if (PACKOUT) {
        int* base = out + (size_t)n * outstr + (size_t)(cob * 2) * OPL + (size_t)h * OPW + w0;
#pragma unroll
        for (int t = 0; t < 4; ++t) {
            if (w0 + t < OW) {
                const int lo = (acc[0][t] & 31) | ((acc[1][t] & 31) << 8)
                             | ((acc[2][t] & 31) << 16) | ((acc[3][t] & 31) << 24);
                const int hi = (acc[4][t] & 31) | ((acc[5][t] & 31) << 8)
                             | ((acc[6][t] & 31) << 16) | ((acc[7][t] & 31) << 24);
                base[t] = lo;
                base[OPL + t] = hi;
            }
        }
        if (wb == WB - 1) {
            for (int pw = OW; pw < OPW; ++pw) { base[pw - w0] = 0; base[OPL + pw - w0] = 0; }
        }
    } else {
        int* ob = out + (size_t)n * outstr;
#pragma unroll
        for (int c = 0; c < 8; ++c) {
            int* row = ob + (size_t)(co0 + c) * OPL + (size_t)h * OPW;
#pragma unroll
            for (int t = 0; t < 4; ++t)
                if (w0 + t < OW) row[w0 + t] = acc[c][t];
            if (wb == WB - 1) { for (int pw = OW; pw < OPW; ++pw) row[pw] = 0; }
        }
    }
}

// ---- weight packing ------------------------------------------------------
__global__ void pack_wf_k(const float* __restrict__ w, float* __restrict__ out,
                          int CIN, int TC, int total)
{
    const int i = blockIdx.x * 256 + threadIdx.x;
    if (i >= total) return;
    const int r = i % 9;
    const int c = (i / 9) % TC;
    const int t = i / (9 * TC);
    const int ci = t % CIN;
    const int cob = t / CIN;
    out[i] = w[(((size_t)cob * TC + c) * CIN + ci) * 9 + r];
}

__global__ void pack_wq_k(const int* __restrict__ q, int* __restrict__ out,
                          int CIN4, int total)
{
    const int i = blockIdx.x * 256 + threadIdx.x;
    if (i >= total) return;
    const int r = i % 9;
    const int c = (i / 9) % 8;
    const int t = i / 72;
    const int ci4 = t % CIN4;
    const int cob = t / CIN4;
    const int co = cob * 8 + c;
    const int* p = q + ((size_t)co * CIN4 * 4 + ci4 * 4) * 9 + r;
    out[i] = (p[0] & 255) | ((p[9] & 255) << 8) | ((p[18] & 255) << 16) | ((p[27] & 255) << 24);
}

// ---- pack DC activations (raw int planes -> i8x4 planes, &31) ------------
template<int CIN,int PH,int PW>
__global__ void pack_a_k(const int* __restrict__ in, int instr,
                         int* __restrict__ out, int outstr, int total)
{
    const int i = blockIdx.x * 256 + threadIdx.x;
    if (i >= total) return;
    constexpr int CIN4 = CIN / 4;
    constexpr int PL = PH * PW;
    int t = i;
    const int pw = t % PW; t /= PW;
    const int ph = t % PH; t /= PH;
    const int c4 = t % CIN4; const int n = t / CIN4;
    const int* p = in + (size_t)n * instr + ((size_t)(c4 * 4) * PH + ph) * PW + pw;
    out[(size_t)n * outstr + ((size_t)c4 * PH + ph) * PW + pw] =
        (p[0] & 31) | ((p[PL] & 31) << 8) | ((p[2 * PL] & 31) << 16) | ((p[3 * PL] & 31) << 24);
}

// ---- int maxpool 2x2/2 into padded dest ----------------------------------
template<int C,int HI,int WI,int HO,int WO,int OPH,int OPW>
__global__ void pool_i_k(const int* __restrict__ in, int instr,
                         int* __restrict__ out, int outstr, int total)
{
    const int i = blockIdx.x * 256 + threadIdx.x;
    if (i >= total) return;
    constexpr int OPL = OPH * OPW;
    int t = i;
    const int px = t % OPW; t /= OPW;
    const int py = t % OPH; t /= OPH;
    const int c  = t % C;   const int n = t / C;
    int v = 0;
    if (py < HO && px < WO) {
        const int* p = in + (size_t)n * instr + ((size_t)c * HI + 2 * py) * WI + 2 * px;
        int m = p[0];
        m = m > p[1] ? m : p[1];
        m = m > p[WI] ? m : p[WI];
        m = m > p[WI + 1] ? m : p[WI + 1];
        v = m;
    }
    out[(size_t)n * outstr + (size_t)c * OPL + (size_t)py * OPW + px] = v;
}

// ---- copy x into padded (3,228,232) --------------------------------------
__global__ void copyin_k(const float* __restrict__ x, float* __restrict__ dst,
                         int outstr, int total)
{
    const int i = blockIdx.x * 256 + threadIdx.x;
    if (i >= total) return;
    int t = i;
    const int pw = t % 232; t /= 232;
    const int ph = t % 228; t /= 228;
    const int c  = t % 3;   const int n = t / 3;
    float v = 0.f;
    const int y = ph - 2, xx = pw - 2;
    if ((unsigned)y < 224u && (unsigned)xx < 224u)
        v = x[(size_t)n * 150528 + ((size_t)c * 224 + y) * 224 + xx];
    dst[(size_t)n * outstr + ((size_t)c * 228 + ph) * 232 + pw] = v;
}

// ---- head ----------------------------------------------------------------
__global__ void pool_mean_k(const int* __restrict__ in, int instr,
                            float* __restrict__ out, int outstr, int total)
{
    const int i = blockIdx.x * 256 + threadIdx.x;
    if (i >= total) return;
    const int n = i / 512, c = i % 512;
    const int* p = in + (size_t)n * instr + (size_t)c * 33;
    int s = 0;
#pragma unroll
    for (int j = 0; j < 33; ++j) s += p[j];
    out[(size_t)n * outstr + c] = (float)s / 33.0f;
}

__global__ void fc_k(const float* __restrict__ pooled, const float* __restrict__ w,
                     const float* __restrict__ b, float* __restrict__ out,
                     int nb, int n0)
{
    const int i = blockIdx.x * 256 + threadIdx.x;
    if (i >= nb * 1000) return;
    const int co = i % 1000;
    const int n  = i / 1000;
    const float* pv = pooled + (size_t)n * 512;
    const float* wr = w + (size_t)co * 512;
    float s = b[co];
    for (int c = 0; c < 512; ++c) s = fmaf(pv[c], wr[c], s);
    out[(size_t)(n0 + n) * 1000 + co] = s;
}

// ---------------------------------------------------------------------------
extern "C" void kernel_launch(void* const* d_in, const int* in_sizes, int n_in,
                              void* d_out, int out_size, void* d_ws, size_t ws_size,
                              hipStream_t stream)
{
    (void)n_in; (void)out_size;
    const float* x = (const float*)d_in[0];
    const float* W[7]; const float* Bv[7]; const int* Q[6];
    const bool inter = (in_sizes[2] == 64);
    for (int i = 0; i < 7; ++i) {
        if (inter) { W[i] = (const float*)d_in[1 + 2 * i]; Bv[i] = (const float*)d_in[2 + 2 * i]; }
        else       { W[i] = (const float*)d_in[1 + i];     Bv[i] = (const float*)d_in[8 + i];     }
    }
    for (int i = 0; i < 6; ++i) Q[i] = (const int*)d_in[15 + i];
    const float* fcw = (const float*)d_in[21];
    const float* fcb = (const float*)d_in[22];
    float* outp = (float*)d_out;

    // ---- packed weights at workspace start ----
    static const int FCO[7]  = {64, 64, 128, 128, 256, 256, 256};
    static const int FCIN[7] = {3, 64, 64, 128, 128, 256, 256};
    static const int FTC[7]  = {8, 4, 8, 4, 8, 8, 4};
    static const int QCIN4[6] = {64, 128, 128, 128, 128, 128};
    size_t wfoff[7], wft = 0;
    for (int i = 0; i < 7; ++i) { wfoff[i] = wft; wft += (size_t)FCO[i] * FCIN[i] * 9; }
    size_t wqoff[6], wqt = 0;
    for (int i = 0; i < 6; ++i) { wqoff[i] = wqt; wqt += (size_t)512 * QCIN4[i] * 9 * 4; }
    const size_t WTOT = wft + wqt;              // 4,978,368 elements

    float* wfb = (float*)d_ws;
    int*   wqb = (int*)((float*)d_ws + wft);
    for (int i = 0; i < 7; ++i) {
        const int total = FCO[i] * FCIN[i] * 9;
        pack_wf_k<<<(total + 255) / 256, 256, 0, stream>>>(W[i], wfb + wfoff[i], FCIN[i], FTC[i], total);
    }
    for (int i = 0; i < 6; ++i) {
        const int total = 512 * QCIN4[i] * 9;
        pack_wq_k<<<(total + 255) / 256, 256, 0, stream>>>(Q[i], wqb + wqoff[i], QCIN4[i], total);
    }

    // ---- arena & per-image tensor sizes (elements) ----
    const long long SZ_X0 = 158688,  SZ_F1 = 3532800, SZ_P1 = 936448;
    const long long SZ_F4 = 2027520, SZ_P2 = 580608,  SZ_F7 = 1264640;
    const long long SZ_F8 = 1440768, SZ_I0 = 360448,  SZ_PK1 = 90112;
    const long long SZ_D1 = 168960,  SZ_D2 = 157696,  SZ_D3 = 532480;
    const long long SZ_P4 = 159744,  SZ_PK4 = 39936,  SZ_D4 = 33792;
    const long long SZ_D5 = 27648,   SZ_D6 = 86016,   SZ_P5 = 16896;

    float* AR = (float*)d_ws + WTOT;
    long long AE2 = ((long long)(ws_size / 4) - (long long)WTOT - 20480) & ~3LL;

    // stage-B batch size
    int nbB = 16;
    for (;; nbB >>= 1) {
        if (nbB == 1) break;
        const long long f = nbB;
        const long long low = (nbB == 16) ? 0 : SZ_P1 * 16;
        const bool ok = (SZ_P1 * 16 + SZ_F4 * f <= AE2)
                     && (low + SZ_P2 * f <= AE2 - SZ_F4 * f)
                     && (low + SZ_F8 * f <= AE2 - SZ_F7 * f)
                     && (low + (SZ_PK1 + SZ_D1 + SZ_D2 + SZ_D3) * f <= AE2);
        if (ok) break;
    }
    // stage-A chunk
    int cA = 16;
    while (cA > 1 && SZ_P1 * 16 + (SZ_X0 + SZ_F1) * cA > AE2) cA >>= 1;

    const long long lowb = (nbB == 16) ? 0 : SZ_P1 * 16;
    float* tP1 = AR;                                       // @0, full 16
    float* tX0 = AR + SZ_P1 * 16;
    float* tF1 = tX0 + SZ_X0 * cA;
    float* tF4 = AR + (AE2 - SZ_F4 * nbB);
    float* tP2 = AR + lowb;
    float* tF7 = AR + (AE2 - SZ_F7 * nbB);
    float* tF8 = AR + lowb;
    int*   tI0 = (int*)(AR + (AE2 - SZ_I0 * nbB));
    int*   tPK1 = (int*)(AR + lowb);
    int*   tD1 = tPK1 + SZ_PK1 * nbB;
    int*   tD2 = tD1 + SZ_D1 * nbB;
    int*   tD3 = tD2 + SZ_D2 * nbB;
    int*   tP4 = (int*)(AR + lowb);
    int*   tPK4 = tP4 + SZ_P4 * nbB;
    int*   tD4 = tPK4 + SZ_PK4 * nbB;
    int*   tD5 = tD4 + SZ_D4 * nbB;
    int*   tD6 = tD5 + SZ_D5 * nbB;
    int*   tP5 = (int*)(AR + lowb);
    float* tPP = (float*)(tP5 + SZ_P5 * nbB);

    // ---- stage A: copyin, L1, L2+pool -> P1ALL ----
    for (int a0 = 0; a0 < 16; a0 += cA) {
        const int nb = cA;
        {
            const int total = nb * 3 * 228 * 232;
            copyin_k<<<(total + 255) / 256, 256, 0, stream>>>(
                x + (size_t)a0 * 150528, tX0, (int)SZ_X0, total);
        }
        {   // L1: X0 -> F1 (64,230,240) border
            const int total = nb * 226 * 58;
            dim3 g((total + 255) / 256, 1, 8);
            convf_k<3, 228, 232, 226, 230, 240, true><<<g, 256, 0, stream>>>(
                tX0, (int)SZ_X0, wfb + wfoff[0], Bv[0], tF1, (int)SZ_F1, total);
        }
        {   // L2 + pool: F1 -> P1ALL (64,118,124) border
            const int total = nb * 114 * 59;
            dim3 g((total + 255) / 256, 1, 16);
            convfp_k<64, 230, 240, 114, 118, 124, 2, 2, false><<<g, 256, 0, stream>>>(
                tF1, (int)SZ_F1, wfb + wfoff[1], Bv[1],
                tP1 + (size_t)a0 * SZ_P1, (int)SZ_P1, total);
        }
    }

    // ---- stage B ----
    for (int b0 = 0; b0 < 16; b0 += nbB) {
        const int nb = nbB;
        {   // L3: P1 -> F4 (128,120,132) border
            const int total = nb * 116 * 31;
            dim3 g((total + 255) / 256, 1, 16);
            convf_k<64, 118, 124, 116, 122, 132, true><<<g, 256, 0, stream>>>(
                tP1 + (size_t)b0 * SZ_P1, (int)SZ_P1, wfb + wfoff[2], Bv[2],
                tF4, (int)SZ_F4, total);
        }
        {   // L4 + pool: F4 -> P2 (128,63,72) border
            const int total = nb * 59 * 32;
            dim3 g((total + 255) / 256, 1, 32);
            convfp_k<128, 120, 132, 59, 64, 72, 2, 2, false><<<g, 256, 0, stream>>>(
                tF4, (int)SZ_F4, wfb + wfoff[3], Bv[3], tP2, (int)SZ_P2, total);
        }
        {   // L5: P2 -> F7 (256,65,76) border
            const int total = nb * 61 * 17;
            dim3 g((total + 255) / 256, 1, 32);
            convf_k<128, 63, 72, 61, 68, 76, true><<<g, 256, 0, stream>>>(
                tP2, (int)SZ_P2, wfb + wfoff[4], Bv[4], tF7, (int)SZ_F7, total);
        }
        {   // L6: F7 -> F8 (256,67,84) border
            const int total = nb * 63 * 19;
            dim3 g((total + 255) / 256, 1, 32);
            convf_k<256, 65, 76, 63, 74, 84, true><<<g, 256, 0, stream>>>(
                tF7, (int)SZ_F7, wfb + wfoff[5], Bv[5], tF8, (int)SZ_F8, total);
        }
        {   // L7 + pool + int: F8 -> I0 (256,32,44)
            const int total = nb * 32 * 20;
            dim3 g((total + 255) / 256, 1, 64);
            convfp_k<256, 67, 84, 32, 40, 44, 0, 0, true><<<g, 256, 0, stream>>>(
                tF8, (int)SZ_F8, wfb + wfoff[6], Bv[6], (void*)tI0, (int)SZ_I0, total);
        }
        {   // pack I0 -> PK1 (64,32,44)
            const int total = nb * 64 * 32 * 44;
            pack_a_k<256, 32, 44><<<(total + 255) / 256, 256, 0, stream>>>(
                tI0, (int)SZ_I0, tPK1, (int)SZ_PK1, total);
        }
        {   // D1: PK1 -> D1 packed (128,30,44)
            const int total = nb * 30 * 10;
            dim3 g((total + 255) / 256, 1, 64);
            convq_k<64, 32, 44, 30, 40, 44, true><<<g, 256, 0, stream>>>(
                tPK1, (int)SZ_PK1, wqb + wqoff[0], tD1, (int)SZ_D1, total);
        }
        {   // D2: D1 -> D2 packed (128,28,44)
            const int total = nb * 28 * 10;
            dim3 g((total + 255) / 256, 1, 64);
            convq_k<128, 30, 44, 28, 40, 44, true><<<g, 256, 0, stream>>>(
                tD1, (int)SZ_D1, wqb + wqoff[1], tD2, (int)SZ_D2, total);
        }
        {   // D3: D2 -> D3 raw (512,26,40)
            const int total = nb * 26 * 10;
            dim3 g((total + 255) / 256, 1, 64);
            convq_k<128, 28, 44, 26, 40, 40, false><<<g, 256, 0, stream>>>(
                tD2, (int)SZ_D2, wqb + wqoff[2], tD3, (int)SZ_D3, total);
        }
        {   // P4: D3 -> P4 raw (512,13,24)
            const int total = nb * 512 * 13 * 24;
            pool_i_k<512, 26, 40, 13, 20, 13, 24><<<(total + 255) / 256, 256, 0, stream>>>(
                tD3, (int)SZ_D3, tP4, (int)SZ_P4, total);
        }
        {   // pack P4 -> PK4 (128,13,24)
            const int total = nb * 128 * 13 * 24;
            pack_a_k<512, 13, 24><<<(total + 255) / 256, 256, 0, stream>>>(
                tP4, (int)SZ_P4, tPK4, (int)SZ_PK4, total);
        }
        {   // D4: PK4 -> D4 packed (128,11,24)
            const int total = nb * 11 * 6;
            dim3 g((total + 255) / 256, 1, 64);
            convq_k<128, 13, 24, 11, 22, 24, true><<<g, 256, 0, stream>>>(
                tPK4, (int)SZ_PK4, wqb + wqoff[3], tD4, (int)SZ_D4, total);
        }
        {   // D5: D4 -> D5 packed (128,9,24)
            const int total = nb * 9 * 6;
            dim3 g((total + 255) / 256, 1, 64);
            convq_k<128, 11, 24, 9, 22, 24, true><<<g, 256, 0, stream>>>(
                tD4, (int)SZ_D4, wqb + wqoff[4], tD5, (int)SZ_D5, total);
        }
        {   // D6: D5 -> D6 raw (512,7,24)
            const int total = nb * 7 * 6;
            dim3 g((total + 255) / 256, 1, 64);
            convq_k<128, 9, 24, 7, 22, 24, false><<<g, 256, 0, stream>>>(
                tD5, (int)SZ_D5, wqb + wqoff[5], tD6, (int)SZ_D6, total);
        }
        {   // P5: D6 -> P5 (512,3,11)
            const int total = nb * 512 * 33;
            pool_i_k<512, 7, 24, 3, 11, 3, 11><<<(total + 255) / 256, 256, 0, stream>>>(
                tD6, (int)SZ_D6, tP5, (int)SZ_P5, total);
        }
        {   // mean -> PP (nb,512)
            const int total = nb * 512;
            pool_mean_k<<<(total + 255) / 256, 256, 0, stream>>>(
                tP5, (int)SZ_P5, tPP, 512, total);
        }
        {   // FC
            const int total = nb * 1000;
            fc_k<<<(total + 255) / 256, 256, 0, stream>>>(tPP, fcw, fcb, outp, nb, b0);
        }
    }
}

// Round 5
// 5998.001 us; speedup vs baseline: 8.5760x; 1.0311x over previous
//
#include <hip/hip_runtime.h>
#include <cstddef>

// ---------------------------------------------------------------------------
// VGG_DC round 5: R4 + (1) grid transpose: co-block = blockIdx.x (fast),
// spatial = blockIdx.z -> co-blocks sharing an input slab run concurrently,
// input read once into L2/L3 instead of once per co-block; (2) ci-loop
// unrolled x2 with true double-buffer role swap (no vb<-vn register copies).
// Per-thread FMA/dot chains identical to R2-R4 -> bit-identical output.
// ---------------------------------------------------------------------------

typedef float v2f __attribute__((ext_vector_type(2)));

static __device__ __forceinline__ int dot4(int a, int b, int c) {
#if __has_builtin(__builtin_amdgcn_sdot4)
    return __builtin_amdgcn_sdot4(a, b, c, false);
#else
    return c + (a & 255) * (b & 255)
             + ((a >> 8) & 255) * ((b >> 8) & 255)
             + ((a >> 16) & 255) * ((b >> 16) & 255)
             + ((a >> 24) & 255) * ((b >> 24) & 255);
#endif
}

static __device__ __forceinline__ void ld6f(const float* __restrict__ p, float v[6]) {
    const float4 a = *reinterpret_cast<const float4*>(p);
    const float2 b = *reinterpret_cast<const float2*>(p + 4);
    v[0] = a.x; v[1] = a.y; v[2] = a.z; v[3] = a.w; v[4] = b.x; v[5] = b.y;
}
static __device__ __forceinline__ void ld6i(const int* __restrict__ p, int v[6]) {
    const int4 a = *reinterpret_cast<const int4*>(p);
    const int2 b = *reinterpret_cast<const int2*>(p + 4);
    v[0] = a.x; v[1] = a.y; v[2] = a.z; v[3] = a.w; v[4] = b.x; v[5] = b.y;
}

// FMA block over one input channel for convf (8 co, 4 w outputs)
static __device__ __forceinline__ void fmac8(const float v[3][6],
                                             const float* __restrict__ wr,
                                             v2f acc[8][2])
{
#pragma unroll
    for (int kh = 0; kh < 3; ++kh) {
        const v2f P0 = {v[kh][0], v[kh][1]};
        const v2f P1 = {v[kh][1], v[kh][2]};
        const v2f P2 = {v[kh][2], v[kh][3]};
        const v2f Q1 = {v[kh][3], v[kh][4]};
        const v2f Q2 = {v[kh][4], v[kh][5]};
#pragma unroll
        for (int c = 0; c < 8; ++c) {
            const float k0 = wr[c * 9 + kh * 3 + 0];
            const float k1 = wr[c * 9 + kh * 3 + 1];
            const float k2 = wr[c * 9 + kh * 3 + 2];
            const v2f k0p = {k0, k0}, k1p = {k1, k1}, k2p = {k2, k2};
            v2f a0 = acc[c][0];
            a0 = __builtin_elementwise_fma(P2, k2p, a0);
            a0 = __builtin_elementwise_fma(P1, k1p, a0);
            a0 = __builtin_elementwise_fma(P0, k0p, a0);
            acc[c][0] = a0;
            v2f a1 = acc[c][1];
            a1 = __builtin_elementwise_fma(Q2, k2p, a1);
            a1 = __builtin_elementwise_fma(Q1, k1p, a1);
            a1 = __builtin_elementwise_fma(P2, k0p, a1);
            acc[c][1] = a1;
        }
    }
}

// FMA block for convfp (4 co, 2 pool-rows x 4 w)
static __device__ __forceinline__ void fmac4p(const float v[4][6],
                                              const float* __restrict__ wr,
                                              v2f acc[4][2][2])
{
#pragma unroll
    for (int r = 0; r < 2; ++r) {
#pragma unroll
        for (int kh = 0; kh < 3; ++kh) {
            const float* vv = v[r + kh];
            const v2f P0 = {vv[0], vv[1]};
            const v2f P1 = {vv[1], vv[2]};
            const v2f P2 = {vv[2], vv[3]};
            const v2f Q1 = {vv[3], vv[4]};
            const v2f Q2 = {vv[4], vv[5]};
#pragma unroll
            for (int c = 0; c < 4; ++c) {
                const float k0 = wr[c * 9 + kh * 3 + 0];
                const float k1 = wr[c * 9 + kh * 3 + 1];
                const float k2 = wr[c * 9 + kh * 3 + 2];
                const v2f k0p = {k0, k0}, k1p = {k1, k1}, k2p = {k2, k2};
                v2f a0 = acc[c][r][0];
                a0 = __builtin_elementwise_fma(P2, k2p, a0);
                a0 = __builtin_elementwise_fma(P1, k1p, a0);
                a0 = __builtin_elementwise_fma(P0, k0p, a0);
                acc[c][r][0] = a0;
                v2f a1 = acc[c][r][1];
                a1 = __builtin_elementwise_fma(Q2, k2p, a1);
                a1 = __builtin_elementwise_fma(Q1, k1p, a1);
                a1 = __builtin_elementwise_fma(P2, k0p, a1);
                acc[c][r][1] = a1;
            }
        }
    }
}

// dot4 block for convq (8 co, 4 w)
static __device__ __forceinline__ void dotc8(const int v[3][6],
                                             const int* __restrict__ wr,
                                             int acc[8][4])
{
#pragma unroll
    for (int kh = 0; kh < 3; ++kh) {
#pragma unroll
        for (int c = 0; c < 8; ++c) {
            const int k0 = wr[c * 9 + kh * 3 + 0];
            const int k1 = wr[c * 9 + kh * 3 + 1];
            const int k2 = wr[c * 9 + kh * 3 + 2];
#pragma unroll
            for (int t = 0; t < 4; ++t)
                acc[c][t] = dot4(v[kh][t], k0,
                            dot4(v[kh][t + 1], k1,
                            dot4(v[kh][t + 2], k2, acc[c][t])));
        }
    }
}

// ---- plain fp32 conv3x3 (pre-padded in/out), 8 co/thread -----------------
// grid: x = co-block (fast), z = spatial chunk
template<int CIN,int PH,int PW,int OH,int OW,int OPW,bool BORDER>
__global__ __launch_bounds__(256) void convf_k(
    const float* __restrict__ in, int instr,
    const float* __restrict__ wfp, const float* __restrict__ bias,
    float* __restrict__ out, int outstr, int total)
{
    constexpr int WB  = (OW + 3) / 4;
    constexpr int OPH = BORDER ? OH + 4 : OH;
    constexpr int OPL = OPH * OPW;
    const int s = blockIdx.z * 256 + threadIdx.x;
    if (s >= total) return;
    const int wb = s % WB;
    const int h  = (s / WB) % OH;
    const int n  = s / (WB * OH);
    const int w0 = wb * 4;
    const int cob = blockIdx.x;
    const int co0 = cob * 8;

    const float* ip = in + (size_t)n * instr + (size_t)h * PW + w0;
    const float* wl = wfp + (size_t)cob * CIN * 72;

    v2f acc[8][2];
#pragma unroll
    for (int c = 0; c < 8; ++c) { acc[c][0] = (v2f)0.f; acc[c][1] = (v2f)0.f; }

    float vb[3][6], vn[3][6];
#pragma unroll
    for (int kh = 0; kh < 3; ++kh) ld6f(ip + kh * PW, vb[kh]);

    if constexpr ((CIN & 1) == 0) {
        for (int ci = 0; ci < CIN; ci += 2) {
            ip += PH * PW;
#pragma unroll
            for (int kh = 0; kh < 3; ++kh) ld6f(ip + kh * PW, vn[kh]);
            fmac8(vb, wl + (size_t)ci * 72, acc);
            ip += PH * PW;                       // last iter: 1-plane overread (guarded arena)
#pragma unroll
            for (int kh = 0; kh < 3; ++kh) ld6f(ip + kh * PW, vb[kh]);
            fmac8(vn, wl + (size_t)(ci + 1) * 72, acc);
        }
    } else {
        for (int ci = 0; ci < CIN; ++ci) {
            ip += PH * PW;
#pragma unroll
            for (int kh = 0; kh < 3; ++kh) ld6f(ip + kh * PW, vn[kh]);
            fmac8(vb, wl + (size_t)ci * 72, acc);
#pragma unroll
            for (int kh = 0; kh < 3; ++kh)
#pragma unroll
                for (int j = 0; j < 6; ++j) vb[kh][j] = vn[kh][j];
        }
    }

    float* ob = out + (size_t)n * outstr;
    const int ph  = BORDER ? h + 2 : h;
    const int pwo = BORDER ? 2 : 0;
#pragma unroll
    for (int c = 0; c < 8; ++c) {
        float* plane = ob + (size_t)(co0 + c) * OPL;
        float* row = plane + (size_t)ph * OPW;
        const float b = bias[co0 + c];
        float av[4] = {acc[c][0][0], acc[c][0][1], acc[c][1][0], acc[c][1][1]};
#pragma unroll
        for (int t = 0; t < 4; ++t)
            if (w0 + t < OW) { const float r = av[t] + b; row[pwo + w0 + t] = r > 0.f ? r : 0.f; }
        if (BORDER) {
            if (wb == 0) { row[0] = 0.f; row[1] = 0.f; }
            if (wb == WB - 1) { for (int pw = OW + 2; pw < OPW; ++pw) row[pw] = 0.f; }
            if (h == 0 || h == OH - 1) {
                float* r0 = plane + (h == 0 ? 0 : (size_t)(OH + 2) * OPW);
                for (int rr = 0; rr < 2; ++rr) {
                    float* br = r0 + (size_t)rr * OPW;
#pragma unroll
                    for (int t = 0; t < 4; ++t) if (w0 + t < OW) br[2 + w0 + t] = 0.f;
                    if (wb == 0) { br[0] = 0.f; br[1] = 0.f; }
                    if (wb == WB - 1) { for (int pw = OW + 2; pw < OPW; ++pw) br[pw] = 0.f; }
                }
            }
        }
    }
}

// ---- fused fp32 conv3x3 + relu + maxpool2 (+optional int cast) -----------
template<int CIN,int PH,int PW,int POH,int POW,int OPW,int OY,int OX,bool TOINT>
__global__ __launch_bounds__(256) void convfp_k(
    const float* __restrict__ in, int instr,
    const float* __restrict__ wfp, const float* __restrict__ bias,
    void* __restrict__ outv, int outstr, int total)
{
    constexpr int WBp = POW / 2;
    constexpr int OPH = POH + 2 * OY;
    constexpr int OPL = OPH * OPW;
    const int s = blockIdx.z * 256 + threadIdx.x;
    if (s >= total) return;
    const int pb = s % WBp;
    const int ph = (s / WBp) % POH;
    const int n  = s / (WBp * POH);
    const int cob = blockIdx.x;
    const int co0 = cob * 4;

    const float* ip = in + (size_t)n * instr + (size_t)(2 * ph) * PW + 4 * pb;
    const float* wl = wfp + (size_t)cob * CIN * 36;

    v2f acc[4][2][2];
#pragma unroll
    for (int c = 0; c < 4; ++c)
#pragma unroll
        for (int r = 0; r < 2; ++r) { acc[c][r][0] = (v2f)0.f; acc[c][r][1] = (v2f)0.f; }

    float vb[4][6], vn[4][6];
#pragma unroll
    for (int r = 0; r < 4; ++r) ld6f(ip + r * PW, vb[r]);

    for (int ci = 0; ci < CIN; ci += 2) {        // CIN always even here
        ip += PH * PW;
#pragma unroll
        for (int r = 0; r < 4; ++r) ld6f(ip + r * PW, vn[r]);
        fmac4p(vb, wl + (size_t)ci * 36, acc);
        ip += PH * PW;
#pragma unroll
        for (int r = 0; r < 4; ++r) ld6f(ip + r * PW, vb[r]);
        fmac4p(vn, wl + (size_t)(ci + 1) * 36, acc);
    }

#pragma unroll
    for (int c = 0; c < 4; ++c) {
        const float b = bias[co0 + c];
        float r00 = acc[c][0][0][0] + b; r00 = r00 > 0.f ? r00 : 0.f;
        float r01 = acc[c][0][0][1] + b; r01 = r01 > 0.f ? r01 : 0.f;
        float r02 = acc[c][0][1][0] + b; r02 = r02 > 0.f ? r02 : 0.f;
        float r03 = acc[c][0][1][1] + b; r03 = r03 > 0.f ? r03 : 0.f;
        float r10 = acc[c][1][0][0] + b; r10 = r10 > 0.f ? r10 : 0.f;
        float r11 = acc[c][1][0][1] + b; r11 = r11 > 0.f ? r11 : 0.f;
        float r12 = acc[c][1][1][0] + b; r12 = r12 > 0.f ? r12 : 0.f;
        float r13 = acc[c][1][1][1] + b; r13 = r13 > 0.f ? r13 : 0.f;
        float p0 = r00; p0 = p0 > r01 ? p0 : r01; p0 = p0 > r10 ? p0 : r10; p0 = p0 > r11 ? p0 : r11;
        float p1 = r02; p1 = p1 > r03 ? p1 : r03; p1 = p1 > r12 ? p1 : r12; p1 = p1 > r13 ? p1 : r13;

        if constexpr (TOINT) {
            int* plane = (int*)outv + (size_t)n * outstr + (size_t)(co0 + c) * OPL;
            int* row = plane + (size_t)(OY + ph) * OPW;
            row[OX + 2 * pb]     = (int)p0;
            row[OX + 2 * pb + 1] = (int)p1;
            if (pb == WBp - 1) { for (int pw = OX + POW; pw < OPW; ++pw) row[pw] = 0; }
        } else {
            float* plane = (float*)outv + (size_t)n * outstr + (size_t)(co0 + c) * OPL;
            float* row = plane + (size_t)(OY + ph) * OPW;
            row[OX + 2 * pb]     = p0;
            row[OX + 2 * pb + 1] = p1;
            if (OX > 0 && pb == 0) { row[0] = 0.f; row[1] = 0.f; }
            if (pb == WBp - 1) { for (int pw = OX + POW; pw < OPW; ++pw) row[pw] = 0.f; }
            if (OY > 0 && (ph == 0 || ph == POH - 1)) {
                float* r0 = plane + (ph == 0 ? 0 : (size_t)(OY + POH) * OPW);
                for (int rr = 0; rr < OY; ++rr) {
                    float* br = r0 + (size_t)rr * OPW;
                    br[OX + 2 * pb] = 0.f; br[OX + 2 * pb + 1] = 0.f;
                    if (pb == 0) { br[0] = 0.f; br[1] = 0.f; }
                    if (pb == WBp - 1) { for (int pw = OX + POW; pw < OPW; ++pw) br[pw] = 0.f; }
                }
            }
        }
    }
}

// ---- int DC conv3x3 (valid) on i8x4-packed input -------------------------
template<int CIN4,int PH,int PW,int OH,int OW,int OPW,bool PACKOUT>
__global__ __launch_bounds__(256) void convq_k(
    const int* __restrict__ in, int instr, const int* __restrict__ wqp,
    int* __restrict__ out, int outstr, int total)
{
    constexpr int WB  = (OW + 3) / 4;
    constexpr int OPL = OH * OPW;
    const int s = blockIdx.z * 256 + threadIdx.x;
    if (s >= total) return;
    const int wb = s % WB;
    const int h  = (s / WB) % OH;
    const int n  = s / (WB * OH);
    const int w0 = wb * 4;
    const int cob = blockIdx.x;
    const int co0 = cob * 8;

    const int* ip = in + (size_t)n * instr + (size_t)h * PW + w0;
    const int* wl = wqp + (size_t)cob * CIN4 * 72;

    int acc[8][4];
#pragma unroll
    for (int c = 0; c < 8; ++c)
#pragma unroll
        for (int t = 0; t < 4; ++t) acc[c][t] = 0;

    int vb[3][6], vn[3][6];
#pragma unroll
    for (int kh = 0; kh < 3; ++kh) ld6i(ip + kh * PW, vb[kh]);

    for (int ci = 0; ci < CIN4; ci += 2) {       // CIN4 always even
        ip += PH * PW;
#pragma unroll
        for (int kh = 0; kh < 3; ++kh) ld6i(ip + kh * PW, vn[kh]);
        dotc8(vb, wl + (size_t)ci * 72, acc);
        ip += PH * PW;
#pragma unroll
        for (int kh = 0; kh < 3; ++kh) ld6i(ip + kh * PW, vb[kh]);
        dotc8(vn, wl + (size_t)(ci + 1) * 72, acc);
    }

    if (PACKOUT) {
        int* base = out + (size_t)n * outstr + (size_t)(cob * 2) * OPL + (size_t)h * OPW + w0;
#pragma unroll
        for (int t = 0; t < 4; ++t) {
            if (w0 + t < OW) {
                const int lo = (acc[0][t] & 31) | ((acc[1][t] & 31) << 8)
                             | ((acc[2][t] & 31) << 16) | ((acc[3][t] & 31) << 24);
                const int hi = (acc[4][t] & 31) | ((acc[5][t] & 31) << 8)
                             | ((acc[6][t] & 31) << 16) | ((acc[7][t] & 31) << 24);
                base[t] = lo;
                base[OPL + t] = hi;
            }
        }
        if (wb == WB - 1) {
            for (int pw = OW; pw < OPW; ++pw) { base[pw - w0] = 0; base[OPL + pw - w0] = 0; }
        }
    } else {
        int* ob = out + (size_t)n * outstr;
#pragma unroll
        for (int c = 0; c < 8; ++c) {
            int* row = ob + (size_t)(co0 + c) * OPL + (size_t)h * OPW;
#pragma unroll
            for (int t = 0; t < 4; ++t)
                if (w0 + t < OW) row[w0 + t] = acc[c][t];
            if (wb == WB - 1) { for (int pw = OW; pw < OPW; ++pw) row[pw] = 0; }
        }
    }
}

// ---- weight packing ------------------------------------------------------
__global__ void pack_wf_k(const float* __restrict__ w, float* __restrict__ out,
                          int CIN, int TC, int total)
{
    const int i = blockIdx.x * 256 + threadIdx.x;
    if (i >= total) return;
    const int r = i % 9;
    const int c = (i / 9) % TC;
    const int t = i / (9 * TC);
    const int ci = t % CIN;
    const int cob = t / CIN;
    out[i] = w[(((size_t)cob * TC + c) * CIN + ci) * 9 + r];
}

__global__ void pack_wq_k(const int* __restrict__ q, int* __restrict__ out,
                          int CIN4, int total)
{
    const int i = blockIdx.x * 256 + threadIdx.x;
    if (i >= total) return;
    const int r = i % 9;
    const int c = (i / 9) % 8;
    const int t = i / 72;
    const int ci4 = t % CIN4;
    const int cob = t / CIN4;
    const int co = cob * 8 + c;
    const int* p = q + ((size_t)co * CIN4 * 4 + ci4 * 4) * 9 + r;
    out[i] = (p[0] & 255) | ((p[9] & 255) << 8) | ((p[18] & 255) << 16) | ((p[27] & 255) << 24);
}

// ---- pack DC activations (raw int planes -> i8x4 planes, &31) ------------
template<int CIN,int PH,int PW>
__global__ void pack_a_k(const int* __restrict__ in, int instr,
                         int* __restrict__ out, int outstr, int total)
{
    const int i = blockIdx.x * 256 + threadIdx.x;
    if (i >= total) return;
    constexpr int CIN4 = CIN / 4;
    constexpr int PL = PH * PW;
    int t = i;
    const int pw = t % PW; t /= PW;
    const int ph = t % PH; t /= PH;
    const int c4 = t % CIN4; const int n = t / CIN4;
    const int* p = in + (size_t)n * instr + ((size_t)(c4 * 4) * PH + ph) * PW + pw;
    out[(size_t)n * outstr + ((size_t)c4 * PH + ph) * PW + pw] =
        (p[0] & 31) | ((p[PL] & 31) << 8) | ((p[2 * PL] & 31) << 16) | ((p[3 * PL] & 31) << 24);
}

// ---- int maxpool 2x2/2 into padded dest ----------------------------------
template<int C,int HI,int WI,int HO,int WO,int OPH,int OPW>
__global__ void pool_i_k(const int* __restrict__ in, int instr,
                         int* __restrict__ out, int outstr, int total)
{
    const int i = blockIdx.x * 256 + threadIdx.x;
    if (i >= total) return;
    constexpr int OPL = OPH * OPW;
    int t = i;
    const int px = t % OPW; t /= OPW;
    const int py = t % OPH; t /= OPH;
    const int c  = t % C;   const int n = t / C;
    int v = 0;
    if (py < HO && px < WO) {
        const int* p = in + (size_t)n * instr + ((size_t)c * HI + 2 * py) * WI + 2 * px;
        int m = p[0];
        m = m > p[1] ? m : p[1];
        m = m > p[WI] ? m : p[WI];
        m = m > p[WI + 1] ? m : p[WI + 1];
        v = m;
    }
    out[(size_t)n * outstr + (size_t)c * OPL + (size_t)py * OPW + px] = v;
}

// ---- copy x into padded (3,228,232) --------------------------------------
__global__ void copyin_k(const float* __restrict__ x, float* __restrict__ dst,
                         int outstr, int total)
{
    const int i = blockIdx.x * 256 + threadIdx.x;
    if (i >= total) return;
    int t = i;
    const int pw = t % 232; t /= 232;
    const int ph = t % 228; t /= 228;
    const int c  = t % 3;   const int n = t / 3;
    float v = 0.f;
    const int y = ph - 2, xx = pw - 2;
    if ((unsigned)y < 224u && (unsigned)xx < 224u)
        v = x[(size_t)n * 150528 + ((size_t)c * 224 + y) * 224 + xx];
    dst[(size_t)n * outstr + ((size_t)c * 228 + ph) * 232 + pw] = v;
}

// ---- head ----------------------------------------------------------------
__global__ void pool_mean_k(const int* __restrict__ in, int instr,
                            float* __restrict__ out, int outstr, int total)
{
    const int i = blockIdx.x * 256 + threadIdx.x;
    if (i >= total) return;
    const int n = i / 512, c = i % 512;
    const int* p = in + (size_t)n * instr + (size_t)c * 33;
    int s = 0;
#pragma unroll
    for (int j = 0; j < 33; ++j) s += p[j];
    out[(size_t)n * outstr + c] = (float)s / 33.0f;
}

__global__ void fc_k(const float* __restrict__ pooled, const float* __restrict__ w,
                     const float* __restrict__ b, float* __restrict__ out,
                     int nb, int n0)
{
    const int i = blockIdx.x * 256 + threadIdx.x;
    if (i >= nb * 1000) return;
    const int co = i % 1000;
    const int n  = i / 1000;
    const float* pv = pooled + (size_t)n * 512;
    const float* wr = w + (size_t)co * 512;
    float s = b[co];
    for (int c = 0; c < 512; ++c) s = fmaf(pv[c], wr[c], s);
    out[(size_t)(n0 + n) * 1000 + co] = s;
}

// ---------------------------------------------------------------------------
extern "C" void kernel_launch(void* const* d_in, const int* in_sizes, int n_in,
                              void* d_out, int out_size, void* d_ws, size_t ws_size,
                              hipStream_t stream)
{
    (void)n_in; (void)out_size;
    const float* x = (const float*)d_in[0];
    const float* W[7]; const float* Bv[7]; const int* Q[6];
    const bool inter = (in_sizes[2] == 64);
    for (int i = 0; i < 7; ++i) {
        if (inter) { W[i] = (const float*)d_in[1 + 2 * i]; Bv[i] = (const float*)d_in[2 + 2 * i]; }
        else       { W[i] = (const float*)d_in[1 + i];     Bv[i] = (const float*)d_in[8 + i];     }
    }
    for (int i = 0; i < 6; ++i) Q[i] = (const int*)d_in[15 + i];
    const float* fcw = (const float*)d_in[21];
    const float* fcb = (const float*)d_in[22];
    float* outp = (float*)d_out;

    // ---- packed weights at workspace start ----
    static const int FCO[7]  = {64, 64, 128, 128, 256, 256, 256};
    static const int FCIN[7] = {3, 64, 64, 128, 128, 256, 256};
    static const int FTC[7]  = {8, 4, 8, 4, 8, 8, 4};
    static const int QCIN4[6] = {64, 128, 128, 128, 128, 128};
    size_t wfoff[7], wft = 0;
    for (int i = 0; i < 7; ++i) { wfoff[i] = wft; wft += (size_t)FCO[i] * FCIN[i] * 9; }
    size_t wqoff[6], wqt = 0;
    for (int i = 0; i < 6; ++i) { wqoff[i] = wqt; wqt += (size_t)512 * QCIN4[i] * 9 * 4; }
    const size_t WTOT = wft + wqt;

    float* wfb = (float*)d_ws;
    int*   wqb = (int*)((float*)d_ws + wft);
    for (int i = 0; i < 7; ++i) {
        const int total = FCO[i] * FCIN[i] * 9;
        pack_wf_k<<<(total + 255) / 256, 256, 0, stream>>>(W[i], wfb + wfoff[i], FCIN[i], FTC[i], total);
    }
    for (int i = 0; i < 6; ++i) {
        const int total = 512 * QCIN4[i] * 9;
        pack_wq_k<<<(total + 255) / 256, 256, 0, stream>>>(Q[i], wqb + wqoff[i], QCIN4[i], total);
    }

    // ---- arena & per-image tensor sizes (elements) ----
    const long long SZ_X0 = 158688,  SZ_F1 = 3532800, SZ_P1 = 936448;
    const long long SZ_F4 = 2027520, SZ_P2 = 580608,  SZ_F7 = 1264640;
    const long long SZ_F8 = 1440768, SZ_I0 = 360448,  SZ_PK1 = 90112;
    const long long SZ_D1 = 168960,  SZ_D2 = 157696,  SZ_D3 = 532480;
    const long long SZ_P4 = 159744,  SZ_PK4 = 39936,  SZ_D4 = 33792;
    const long long SZ_D5 = 27648,   SZ_D6 = 86016,   SZ_P5 = 16896;

    float* AR = (float*)d_ws + WTOT;
    long long AE2 = ((long long)(ws_size / 4) - (long long)WTOT - 20480) & ~3LL;

    int nbB = 16;
    for (;; nbB >>= 1) {
        if (nbB == 1) break;
        const long long f = nbB;
        const long long low = (nbB == 16) ? 0 : SZ_P1 * 16;
        const bool ok = (SZ_P1 * 16 + SZ_F4 * f <= AE2)
                     && (low + SZ_P2 * f <= AE2 - SZ_F4 * f)
                     && (low + SZ_F8 * f <= AE2 - SZ_F7 * f)
                     && (low + (SZ_PK1 + SZ_D1 + SZ_D2 + SZ_D3) * f <= AE2);
        if (ok) break;
    }
    int cA = 16;
    while (cA > 1 && SZ_P1 * 16 + (SZ_X0 + SZ_F1) * cA > AE2) cA >>= 1;

    const long long lowb = (nbB == 16) ? 0 : SZ_P1 * 16;
    float* tP1 = AR;
    float* tX0 = AR + SZ_P1 * 16;
    float* tF1 = tX0 + SZ_X0 * cA;
    float* tF4 = AR + (AE2 - SZ_F4 * nbB);
    float* tP2 = AR + lowb;
    float* tF7 = AR + (AE2 - SZ_F7 * nbB);
    float* tF8 = AR + lowb;
    int*   tI0 = (int*)(AR + (AE2 - SZ_I0 * nbB));
    int*   tPK1 = (int*)(AR + lowb);
    int*   tD1 = tPK1 + SZ_PK1 * nbB;
    int*   tD2 = tD1 + SZ_D1 * nbB;
    int*   tD3 = tD2 + SZ_D2 * nbB;
    int*   tP4 = (int*)(AR + lowb);
    int*   tPK4 = tP4 + SZ_P4 * nbB;
    int*   tD4 = tPK4 + SZ_PK4 * nbB;
    int*   tD5 = tD4 + SZ_D4 * nbB;
    int*   tD6 = tD5 + SZ_D5 * nbB;
    int*   tP5 = (int*)(AR + lowb);
    float* tPP = (float*)(tP5 + SZ_P5 * nbB);

    // ---- stage A: copyin, L1, L2+pool -> P1ALL ----
    for (int a0 = 0; a0 < 16; a0 += cA) {
        const int nb = cA;
        {
            const int total = nb * 3 * 228 * 232;
            copyin_k<<<(total + 255) / 256, 256, 0, stream>>>(
                x + (size_t)a0 * 150528, tX0, (int)SZ_X0, total);
        }
        {   // L1: X0 -> F1 (64,230,240) border
            const int total = nb * 226 * 58;
            dim3 g(8, 1, (total + 255) / 256);
            convf_k<3, 228, 232, 226, 230, 240, true><<<g, 256, 0, stream>>>(
                tX0, (int)SZ_X0, wfb + wfoff[0], Bv[0], tF1, (int)SZ_F1, total);
        }
        {   // L2 + pool: F1 -> P1ALL (64,118,124) border
            const int total = nb * 114 * 59;
            dim3 g(16, 1, (total + 255) / 256);
            convfp_k<64, 230, 240, 114, 118, 124, 2, 2, false><<<g, 256, 0, stream>>>(
                tF1, (int)SZ_F1, wfb + wfoff[1], Bv[1],
                tP1 + (size_t)a0 * SZ_P1, (int)SZ_P1, total);
        }
    }

    // ---- stage B ----
    for (int b0 = 0; b0 < 16; b0 += nbB) {
        const int nb = nbB;
        {   // L3: P1 -> F4 (128,120,132) border
            const int total = nb * 116 * 31;
            dim3 g(16, 1, (total + 255) / 256);
            convf_k<64, 118, 124, 116, 122, 132, true><<<g, 256, 0, stream>>>(
                tP1 + (size_t)b0 * SZ_P1, (int)SZ_P1, wfb + wfoff[2], Bv[2],
                tF4, (int)SZ_F4, total);
        }
        {   // L4 + pool: F4 -> P2 (128,63,72) border
            const int total = nb * 59 * 32;
            dim3 g(32, 1, (total + 255) / 256);
            convfp_k<128, 120, 132, 59, 64, 72, 2, 2, false><<<g, 256, 0, stream>>>(
                tF4, (int)SZ_F4, wfb + wfoff[3], Bv[3], tP2, (int)SZ_P2, total);
        }
        {   // L5: P2 -> F7 (256,65,76) border
            const int total = nb * 61 * 17;
            dim3 g(32, 1, (total + 255) / 256);
            convf_k<128, 63, 72, 61, 68, 76, true><<<g, 256, 0, stream>>>(
                tP2, (int)SZ_P2, wfb + wfoff[4], Bv[4], tF7, (int)SZ_F7, total);
        }
        {   // L6: F7 -> F8 (256,67,84) border
            const int total = nb * 63 * 19;
            dim3 g(32, 1, (total + 255) / 256);
            convf_k<256, 65, 76, 63, 74, 84, true><<<g, 256, 0, stream>>>(
                tF7, (int)SZ_F7, wfb + wfoff[5], Bv[5], tF8, (int)SZ_F8, total);
        }
        {   // L7 + pool + int: F8 -> I0 (256,32,44)
            const int total = nb * 32 * 20;
            dim3 g(64, 1, (total + 255) / 256);
            convfp_k<256, 67, 84, 32, 40, 44, 0, 0, true><<<g, 256, 0, stream>>>(
                tF8, (int)SZ_F8, wfb + wfoff[6], Bv[6], (void*)tI0, (int)SZ_I0, total);
        }
        {   // pack I0 -> PK1 (64,32,44)
            const int total = nb * 64 * 32 * 44;
            pack_a_k<256, 32, 44><<<(total + 255) / 256, 256, 0, stream>>>(
                tI0, (int)SZ_I0, tPK1, (int)SZ_PK1, total);
        }
        {   // D1
            const int total = nb * 30 * 10;
            dim3 g(64, 1, (total + 255) / 256);
            convq_k<64, 32, 44, 30, 40, 44, true><<<g, 256, 0, stream>>>(
                tPK1, (int)SZ_PK1, wqb + wqoff[0], tD1, (int)SZ_D1, total);
        }
        {   // D2
            const int total = nb * 28 * 10;
            dim3 g(64, 1, (total + 255) / 256);
            convq_k<128, 30, 44, 28, 40, 44, true><<<g, 256, 0, stream>>>(
                tD1, (int)SZ_D1, wqb + wqoff[1], tD2, (int)SZ_D2, total);
        }
        {   // D3 (raw out)
            const int total = nb * 26 * 10;
            dim3 g(64, 1, (total + 255) / 256);
            convq_k<128, 28, 44, 26, 40, 40, false><<<g, 256, 0, stream>>>(
                tD2, (int)SZ_D2, wqb + wqoff[2], tD3, (int)SZ_D3, total);
        }
        {   // P4
            const int total = nb * 512 * 13 * 24;
            pool_i_k<512, 26, 40, 13, 20, 13, 24><<<(total + 255) / 256, 256, 0, stream>>>(
                tD3, (int)SZ_D3, tP4, (int)SZ_P4, total);
        }
        {   // pack P4 -> PK4
            const int total = nb * 128 * 13 * 24;
            pack_a_k<512, 13, 24><<<(total + 255) / 256, 256, 0, stream>>>(
                tP4, (int)SZ_P4, tPK4, (int)SZ_PK4, total);
        }
        {   // D4
            const int total = nb * 11 * 6;
            dim3 g(64, 1, (total + 255) / 256);
            convq_k<128, 13, 24, 11, 22, 24, true><<<g, 256, 0, stream>>>(
                tPK4, (int)SZ_PK4, wqb + wqoff[3], tD4, (int)SZ_D4, total);
        }
        {   // D5
            const int total = nb * 9 * 6;
            dim3 g(64, 1, (total + 255) / 256);
            convq_k<128, 11, 24, 9, 22, 24, true><<<g, 256, 0, stream>>>(
                tD4, (int)SZ_D4, wqb + wqoff[4], tD5, (int)SZ_D5, total);
        }
        {   // D6 (raw out)
            const int total = nb * 7 * 6;
            dim3 g(64, 1, (total + 255) / 256);
            convq_k<128, 9, 24, 7, 22, 24, false><<<g, 256, 0, stream>>>(
                tD5, (int)SZ_D5, wqb + wqoff[5], tD6, (int)SZ_D6, total);
        }
        {   // P5
            const int total = nb * 512 * 33;
            pool_i_k<512, 7, 24, 3, 11, 3, 11><<<(total + 255) / 256, 256, 0, stream>>>(
                tD6, (int)SZ_D6, tP5, (int)SZ_P5, total);
        }
        {   // mean -> PP
            const int total = nb * 512;
            pool_mean_k<<<(total + 255) / 256, 256, 0, stream>>>(
                tP5, (int)SZ_P5, tPP, 512, total);
        }
        {   // FC
            const int total = nb * 1000;
            fc_k<<<(total + 255) / 256, 256, 0, stream>>>(tPP, fcw, fcb, outp, nb, b0);
        }
    }
}